// Round 6
// baseline (361.363 us; speedup 1.0000x reference)
//
#include <hip/hip_runtime.h>
#include <hip/hip_bf16.h>

#define N_NODES 50000
#define N_EDGES 800000

// ---------------------------------------------------------------------------
// row_ptr[i] = lower_bound(src, i); src is sorted. row_ptr[N] = E.
// ---------------------------------------------------------------------------
__global__ __launch_bounds__(256) void rowptr_kernel(const int* __restrict__ src,
                                                     int* __restrict__ row_ptr,
                                                     int n, int e) {
    int i = blockIdx.x * 256 + threadIdx.x;
    if (i > n) return;
    int lo = 0, hi = e;
    while (lo < hi) {
        int mid = (lo + hi) >> 1;
        if (src[mid] < i) lo = mid + 1; else hi = mid;
    }
    row_ptr[i] = lo;
}

// ---------------------------------------------------------------------------
// Fold duplicated head-0/1 input columns of lin1_w / lin2_w (64 x 256) into
// planar K=192 weights matching agg's output layout [i, c*64 + f].
// ---------------------------------------------------------------------------
__global__ __launch_bounds__(256) void wprep_kernel(const float* __restrict__ lw1,
                                                    const float* __restrict__ lw2,
                                                    float* __restrict__ w1p,
                                                    float* __restrict__ w2p) {
    int idx = blockIdx.x * 256 + threadIdx.x;
    if (idx >= 64 * 192) return;
    int o = idx / 192, r = idx % 192;
    int c = r >> 6, f = r & 63;
    const float* lw = (blockIdx.y == 0) ? lw1 : lw2;
    float v;
    if (c == 0)      v = lw[o * 256 + f * 4 + 0] + lw[o * 256 + f * 4 + 1];
    else if (c == 1) v = lw[o * 256 + f * 4 + 2];
    else             v = lw[o * 256 + f * 4 + 3];
    (blockIdx.y == 0 ? w1p : w2p)[idx] = v;
}

// ---------------------------------------------------------------------------
// lin: h[i,o] = leaky_relu(x[i,:].w[o,:] + b[o]), o in [0,64).
// 64x64 tile, 128 threads (2 waves), 4x8 per-thread register tile, BK=16.
// Per kk: 3 ds_read_b128 per 32 FMA-inst -> VALU-bound; 782 blocks for
// occupancy (R5's 128x64/8x8 had only 391 blocks -> 5.6% occupancy).
// Fused score epilogue: 8-lane partial-dot reduce (xor 1,2,4 within cg).
// ---------------------------------------------------------------------------
template <int K>
__global__ __launch_bounds__(128) void lin_kernel(const float* __restrict__ in,
                                                  const float* __restrict__ w,
                                                  const float* __restrict__ b,
                                                  const float* __restrict__ aw,
                                                  float* __restrict__ h,
                                                  float2* __restrict__ s, int n) {
    __shared__ float xs[16][64];
    __shared__ float ws[16][64];
    const int t = threadIdx.x;          // 0..127
    const int cg = t & 7;               // col group: cols cg*8 .. cg*8+7
    const int rg = t >> 3;              // row group: rows rg*4 .. rg*4+3
    const long i0 = (long)blockIdx.x * 64;

    float acc[4][8] = {};

    for (int k0 = 0; k0 < K; k0 += 16) {
        __syncthreads();  // protect previous iteration's fragment reads
        #pragma unroll
        for (int q = 0; q < 2; ++q) {
            int p = t + 128 * q;            // 0..255
            int row = p >> 2, kq = p & 3;
            long rr = i0 + row; if (rr >= n) rr = n - 1;
            float4 v = *(const float4*)(in + rr * K + k0 + kq * 4);
            xs[kq * 4 + 0][row] = v.x; xs[kq * 4 + 1][row] = v.y;
            xs[kq * 4 + 2][row] = v.z; xs[kq * 4 + 3][row] = v.w;
        }
        #pragma unroll
        for (int q = 0; q < 2; ++q) {
            int p = t + 128 * q;            // 0..255
            int o = p >> 2, kq = p & 3;
            float4 v = *(const float4*)(w + o * K + k0 + kq * 4);
            ws[kq * 4 + 0][o] = v.x; ws[kq * 4 + 1][o] = v.y;
            ws[kq * 4 + 2][o] = v.z; ws[kq * 4 + 3][o] = v.w;
        }
        __syncthreads();
        #pragma unroll
        for (int kk = 0; kk < 16; ++kk) {
            float4 a  = *(const float4*)&xs[kk][rg * 4];
            float4 b0 = *(const float4*)&ws[kk][cg * 8];
            float4 b1 = *(const float4*)&ws[kk][cg * 8 + 4];
            float av[4] = {a.x, a.y, a.z, a.w};
            float bv[8] = {b0.x, b0.y, b0.z, b0.w, b1.x, b1.y, b1.z, b1.w};
            #pragma unroll
            for (int r = 0; r < 4; ++r)
                #pragma unroll
                for (int c = 0; c < 8; ++c)
                    acc[r][c] += av[r] * bv[c];
        }
    }

    // epilogue: bias + leaky relu + store + fused score
    float bias[8], a2c[8], a3c[8];
    #pragma unroll
    for (int c = 0; c < 8; ++c) {
        int col = cg * 8 + c;
        bias[c] = b[col];
        a2c[c] = aw[2 * 128 + col] + aw[2 * 128 + 64 + col];
        a3c[c] = aw[3 * 128 + col] + aw[3 * 128 + 64 + col];
    }
    #pragma unroll
    for (int r = 0; r < 4; ++r) {
        long row = i0 + rg * 4 + r;
        if (row >= n) break;
        float v[8];
        float q2 = 0.f, q3 = 0.f;
        #pragma unroll
        for (int c = 0; c < 8; ++c) {
            float u = acc[r][c] + bias[c];
            u = u > 0.f ? u : 0.2f * u;
            v[c] = u;
            q2 += u * a2c[c];
            q3 += u * a3c[c];
        }
        *(float4*)(h + row * 64 + cg * 8)     = make_float4(v[0], v[1], v[2], v[3]);
        *(float4*)(h + row * 64 + cg * 8 + 4) = make_float4(v[4], v[5], v[6], v[7]);
        #pragma unroll
        for (int o = 1; o < 8; o <<= 1) {
            q2 += __shfl_xor(q2, o);
            q3 += __shfl_xor(q3, o);
        }
        if (cg == 0) s[row] = make_float2(q2, q3);
    }
}

// ---------------------------------------------------------------------------
// nodestat: per-node softmax max + 1/sum for heads 2,3 (softmax over s[dst];
// ab cancels). Wave per node, 4 nodes/block. stats[i] = {m2, 1/S2, m3, 1/S3}.
// ---------------------------------------------------------------------------
__global__ __launch_bounds__(256) void nodestat_kernel(const float2* __restrict__ s,
                                                       const int* __restrict__ dst,
                                                       const int* __restrict__ row_ptr,
                                                       float4* __restrict__ stats, int n) {
    const int t = threadIdx.x;
    const int l = t & 63;
    const int i = blockIdx.x * 4 + (t >> 6);
    if (i >= n) return;
    const int r0 = row_ptr[i], r1 = row_ptr[i + 1];
    const int deg = r1 - r0;
    if (deg == 0) return;  // stats never read for deg==0 nodes

    if (deg <= 64) {
        float g2 = -INFINITY, g3 = -INFINITY;
        if (l < deg) {
            float2 sv = s[dst[r0 + l]];
            g2 = sv.x; g3 = sv.y;
        }
        float m2 = g2, m3 = g3;
        #pragma unroll
        for (int o = 1; o < 64; o <<= 1) {
            m2 = fmaxf(m2, __shfl_xor(m2, o));
            m3 = fmaxf(m3, __shfl_xor(m3, o));
        }
        float S2 = (l < deg) ? __expf(g2 - m2) : 0.f;
        float S3 = (l < deg) ? __expf(g3 - m3) : 0.f;
        #pragma unroll
        for (int o = 1; o < 64; o <<= 1) { S2 += __shfl_xor(S2, o); S3 += __shfl_xor(S3, o); }
        if (l == 0) stats[i] = make_float4(m2, 1.f / S2, m3, 1.f / S3);
    } else {
        float m2 = -INFINITY, m3 = -INFINITY;
        for (int e = r0 + l; e < r1; e += 64) {
            float2 sv = s[dst[e]];
            m2 = fmaxf(m2, sv.x); m3 = fmaxf(m3, sv.y);
        }
        #pragma unroll
        for (int o = 1; o < 64; o <<= 1) {
            m2 = fmaxf(m2, __shfl_xor(m2, o));
            m3 = fmaxf(m3, __shfl_xor(m3, o));
        }
        float S2 = 0.f, S3 = 0.f;
        for (int e = r0 + l; e < r1; e += 64) {
            float2 sv = s[dst[e]];
            S2 += __expf(sv.x - m2); S3 += __expf(sv.y - m3);
        }
        #pragma unroll
        for (int o = 1; o < 64; o <<= 1) { S2 += __shfl_xor(S2, o); S3 += __shfl_xor(S3, o); }
        if (l == 0) stats[i] = make_float4(m2, 1.f / S2, m3, 1.f / S3);
    }
}

// ---------------------------------------------------------------------------
// edgeprep: thread per edge, fully coalesced except the two small gathers.
// w23[e] = { alpha2(e), alpha3(e) } (normalized).
// ---------------------------------------------------------------------------
__global__ __launch_bounds__(256) void edgeprep_kernel(const float2* __restrict__ s,
                                                       const int* __restrict__ src,
                                                       const int* __restrict__ dst,
                                                       const float4* __restrict__ stats,
                                                       float2* __restrict__ w23, int e_total) {
    int e = blockIdx.x * 256 + threadIdx.x;
    if (e >= e_total) return;
    int d = dst[e];
    float2 sv = s[d];
    float4 st = stats[src[e]];   // src sorted -> mostly L1-hit broadcast
    w23[e] = make_float2(__expf(sv.x - st.x) * st.y, __expf(sv.y - st.z) * st.w);
}

// ---------------------------------------------------------------------------
// aggregate: wave per node, lane = feature. Edge scalars (dst, w2, w3) loaded
// at wave-uniform addresses (readfirstlane-rooted) -> scalar loads, weights
// applied as SGPR operands: per-edge VALU = 3 v_fmac only. hfeat row gather
// is the single coalesced vector load per edge. Masked 8-blocks: 8 loads in
// flight, no serial tail (invalid slots: clamped index, scalar-zeroed weight).
// ---------------------------------------------------------------------------
__global__ __launch_bounds__(256) void aggregate_kernel(const float* __restrict__ hfeat,
                                                        const int* __restrict__ dst,
                                                        const float2* __restrict__ w23,
                                                        const int* __restrict__ row_ptr,
                                                        float* __restrict__ out,
                                                        int final_layer, int n) {
    const int t = threadIdx.x;
    const int l = t & 63;
    const int i = blockIdx.x * 4 + (t >> 6);
    if (i >= n) return;
    const int r0 = __builtin_amdgcn_readfirstlane(row_ptr[i]);
    const int r1 = __builtin_amdgcn_readfirstlane(row_ptr[i + 1]);
    const int deg = r1 - r0;

    if (deg == 0) {
        if (!final_layer) {
            out[(long)i * 192 + l] = 0.f;
            out[(long)i * 192 + 64 + l] = 0.f;
            out[(long)i * 192 + 128 + l] = 0.f;
        } else {
            out[(long)i * 64 + l] = 0.f;
        }
        return;
    }

    const float inv_deg = 1.f / (float)deg;
    float accm = 0.f, acc2 = 0.f, acc3 = 0.f;

    for (int j = r0; j < r1; j += 8) {
        int dd[8];
        float wm[8], w2[8], w3[8];
        #pragma unroll
        for (int q = 0; q < 8; ++q) {
            int jq = j + q;
            int jc = jq < r1 ? jq : r1 - 1;   // scalar clamp
            dd[q] = dst[jc];                  // uniform -> s_load
            float2 wv = w23[jc];              // uniform -> s_load_dwordx2
            bool valid = jq < r1;
            wm[q] = valid ? 1.f : 0.f;        // scalar select
            w2[q] = valid ? wv.x : 0.f;
            w3[q] = valid ? wv.y : 0.f;
        }
        float hv[8];
        #pragma unroll
        for (int q = 0; q < 8; ++q) hv[q] = hfeat[(long)dd[q] * 64 + l];
        #pragma unroll
        for (int q = 0; q < 8; ++q) {
            accm += wm[q] * hv[q];
            acc2 += w2[q] * hv[q];
            acc3 += w3[q] * hv[q];
        }
    }

    if (!final_layer) {
        out[(long)i * 192 + l]       = fmaxf(accm * inv_deg, 0.f);
        out[(long)i * 192 + 64 + l]  = fmaxf(acc2, 0.f);
        out[(long)i * 192 + 128 + l] = fmaxf(acc3, 0.f);
    } else {
        out[(long)i * 64 + l] = fmaxf(0.5f * inv_deg * accm + 0.25f * (acc2 + acc3), 0.f);
    }
}

// ---------------------------------------------------------------------------
extern "C" void kernel_launch(void* const* d_in, const int* in_sizes, int n_in,
                              void* d_out, int out_size, void* d_ws, size_t ws_size,
                              hipStream_t stream) {
    const float* x = (const float*)d_in[0];
    const float* lw[3] = {(const float*)d_in[1], (const float*)d_in[5], (const float*)d_in[9]};
    const float* lb[3] = {(const float*)d_in[2], (const float*)d_in[6], (const float*)d_in[10]};
    const float* aw[3] = {(const float*)d_in[3], (const float*)d_in[7], (const float*)d_in[11]};
    const int* src = (const int*)d_in[13];
    const int* dst = (const int*)d_in[14];
    float* out = (float*)d_out;

    const int N = N_NODES, E = N_EDGES;

    // ws layout (floats):
    //   bufA[N*192] | hbuf[N*64] | sbuf[N*2] | stats[N*4] | w23[E*2]
    //   | w1p[64*192] | w2p[64*192] | row_ptr[N+1]          (~59 MB total)
    float* bufA = (float*)d_ws;
    float* hbuf = bufA + (size_t)N * 192;
    float2* sbuf = (float2*)(hbuf + (size_t)N * 64);
    float4* stats = (float4*)(sbuf + N);
    float2* w23 = (float2*)(stats + N);
    float* w1p = (float*)(w23 + E);
    float* w2p = w1p + 64 * 192;
    int* row_ptr = (int*)(w2p + 64 * 192);

    rowptr_kernel<<<(N + 1 + 255) / 256, 256, 0, stream>>>(src, row_ptr, N, E);
    wprep_kernel<<<dim3(48, 2), 256, 0, stream>>>(lw[1], lw[2], w1p, w2p);

    const int lin_grid = (N + 63) / 64;
    const int node_grid = (N + 3) / 4;
    const int edge_grid = (E + 255) / 256;

    // ---- layer 0 ----
    lin_kernel<128><<<lin_grid, 128, 0, stream>>>(x, lw[0], lb[0], aw[0], hbuf, sbuf, N);
    nodestat_kernel<<<node_grid, 256, 0, stream>>>(sbuf, dst, row_ptr, stats, N);
    edgeprep_kernel<<<edge_grid, 256, 0, stream>>>(sbuf, src, dst, stats, w23, E);
    aggregate_kernel<<<node_grid, 256, 0, stream>>>(hbuf, dst, w23, row_ptr, bufA, 0, N);

    // ---- layer 1 ----
    lin_kernel<192><<<lin_grid, 128, 0, stream>>>(bufA, w1p, lb[1], aw[1], hbuf, sbuf, N);
    nodestat_kernel<<<node_grid, 256, 0, stream>>>(sbuf, dst, row_ptr, stats, N);
    edgeprep_kernel<<<edge_grid, 256, 0, stream>>>(sbuf, src, dst, stats, w23, E);
    aggregate_kernel<<<node_grid, 256, 0, stream>>>(hbuf, dst, w23, row_ptr, bufA, 0, N);

    // ---- layer 2 (final) ----
    lin_kernel<192><<<lin_grid, 128, 0, stream>>>(bufA, w2p, lb[2], aw[2], hbuf, sbuf, N);
    nodestat_kernel<<<node_grid, 256, 0, stream>>>(sbuf, dst, row_ptr, stats, N);
    edgeprep_kernel<<<edge_grid, 256, 0, stream>>>(sbuf, src, dst, stats, w23, E);
    aggregate_kernel<<<node_grid, 256, 0, stream>>>(hbuf, dst, w23, row_ptr, out, 1, N);
}

// Round 7
// 338.554 us; speedup vs baseline: 1.0674x; 1.0674x over previous
//
#include <hip/hip_runtime.h>
#include <hip/hip_fp16.h>

#define N_NODES 50000
#define N_EDGES 800000

// ---------------------------------------------------------------------------
// row_ptr[i] = lower_bound(src, i); src is sorted. row_ptr[N] = E.
// ---------------------------------------------------------------------------
__global__ __launch_bounds__(256) void rowptr_kernel(const int* __restrict__ src,
                                                     int* __restrict__ row_ptr,
                                                     int n, int e) {
    int i = blockIdx.x * 256 + threadIdx.x;
    if (i > n) return;
    int lo = 0, hi = e;
    while (lo < hi) {
        int mid = (lo + hi) >> 1;
        if (src[mid] < i) lo = mid + 1; else hi = mid;
    }
    row_ptr[i] = lo;
}

// ---------------------------------------------------------------------------
// Fold duplicated head-0/1 input columns of lin1_w / lin2_w (64 x 256) into
// planar K=192 weights matching agg's output layout [i, c*64 + f].
// ---------------------------------------------------------------------------
__global__ __launch_bounds__(256) void wprep_kernel(const float* __restrict__ lw1,
                                                    const float* __restrict__ lw2,
                                                    float* __restrict__ w1p,
                                                    float* __restrict__ w2p) {
    int idx = blockIdx.x * 256 + threadIdx.x;
    if (idx >= 64 * 192) return;
    int o = idx / 192, r = idx % 192;
    int c = r >> 6, f = r & 63;
    const float* lw = (blockIdx.y == 0) ? lw1 : lw2;
    float v;
    if (c == 0)      v = lw[o * 256 + f * 4 + 0] + lw[o * 256 + f * 4 + 1];
    else if (c == 1) v = lw[o * 256 + f * 4 + 2];
    else             v = lw[o * 256 + f * 4 + 3];
    (blockIdx.y == 0 ? w1p : w2p)[idx] = v;
}

// ---------------------------------------------------------------------------
// lin: h[i,o] = leaky_relu(x[i,:].w[o,:] + b[o]), o in [0,64).  h stored FP16.
// 64x64 tile, 128 threads (2 waves), 4x8 per-thread register tile, BK=16.
// Fused score epilogue (fp32): s[i] = (h_i.(aw2L+aw2R), h_i.(aw3L+aw3R)).
// ---------------------------------------------------------------------------
template <int K>
__global__ __launch_bounds__(128) void lin_kernel(const float* __restrict__ in,
                                                  const float* __restrict__ w,
                                                  const float* __restrict__ b,
                                                  const float* __restrict__ aw,
                                                  __half* __restrict__ h,
                                                  float2* __restrict__ s, int n) {
    __shared__ float xs[16][64];
    __shared__ float ws[16][64];
    const int t = threadIdx.x;          // 0..127
    const int cg = t & 7;               // col group: cols cg*8 .. cg*8+7
    const int rg = t >> 3;              // row group: rows rg*4 .. rg*4+3
    const long i0 = (long)blockIdx.x * 64;

    float acc[4][8] = {};

    for (int k0 = 0; k0 < K; k0 += 16) {
        __syncthreads();  // protect previous iteration's fragment reads
        #pragma unroll
        for (int q = 0; q < 2; ++q) {
            int p = t + 128 * q;            // 0..255
            int row = p >> 2, kq = p & 3;
            long rr = i0 + row; if (rr >= n) rr = n - 1;
            float4 v = *(const float4*)(in + rr * K + k0 + kq * 4);
            xs[kq * 4 + 0][row] = v.x; xs[kq * 4 + 1][row] = v.y;
            xs[kq * 4 + 2][row] = v.z; xs[kq * 4 + 3][row] = v.w;
        }
        #pragma unroll
        for (int q = 0; q < 2; ++q) {
            int p = t + 128 * q;            // 0..255
            int o = p >> 2, kq = p & 3;
            float4 v = *(const float4*)(w + o * K + k0 + kq * 4);
            ws[kq * 4 + 0][o] = v.x; ws[kq * 4 + 1][o] = v.y;
            ws[kq * 4 + 2][o] = v.z; ws[kq * 4 + 3][o] = v.w;
        }
        __syncthreads();
        #pragma unroll
        for (int kk = 0; kk < 16; ++kk) {
            float4 a  = *(const float4*)&xs[kk][rg * 4];
            float4 b0 = *(const float4*)&ws[kk][cg * 8];
            float4 b1 = *(const float4*)&ws[kk][cg * 8 + 4];
            float av[4] = {a.x, a.y, a.z, a.w};
            float bv[8] = {b0.x, b0.y, b0.z, b0.w, b1.x, b1.y, b1.z, b1.w};
            #pragma unroll
            for (int r = 0; r < 4; ++r)
                #pragma unroll
                for (int c = 0; c < 8; ++c)
                    acc[r][c] += av[r] * bv[c];
        }
    }

    // epilogue: bias + leaky relu + fp16 store + fused score
    float bias[8], a2c[8], a3c[8];
    #pragma unroll
    for (int c = 0; c < 8; ++c) {
        int col = cg * 8 + c;
        bias[c] = b[col];
        a2c[c] = aw[2 * 128 + col] + aw[2 * 128 + 64 + col];
        a3c[c] = aw[3 * 128 + col] + aw[3 * 128 + 64 + col];
    }
    #pragma unroll
    for (int r = 0; r < 4; ++r) {
        long row = i0 + rg * 4 + r;
        if (row >= n) break;
        float q2 = 0.f, q3 = 0.f;
        union { __half2 h2[4]; float4 f4; } pk;
        #pragma unroll
        for (int c = 0; c < 8; c += 2) {
            float u0 = acc[r][c] + bias[c];
            float u1 = acc[r][c + 1] + bias[c + 1];
            u0 = u0 > 0.f ? u0 : 0.2f * u0;
            u1 = u1 > 0.f ? u1 : 0.2f * u1;
            pk.h2[c >> 1] = __floats2half2_rn(u0, u1);
            q2 += u0 * a2c[c] + u1 * a2c[c + 1];
            q3 += u0 * a3c[c] + u1 * a3c[c + 1];
        }
        *(float4*)(h + row * 64 + cg * 8) = pk.f4;   // 16B store of 8 halves
        #pragma unroll
        for (int o = 1; o < 8; o <<= 1) {
            q2 += __shfl_xor(q2, o);
            q3 += __shfl_xor(q3, o);
        }
        if (cg == 0) s[row] = make_float2(q2, q3);
    }
}

// ---------------------------------------------------------------------------
// prep: per-node softmax stats AND per-edge normalized weights in one pass.
// Wave per node. The wave gathering s[dst[e]] for node i's softmax holds
// exactly the values needed for w23[r0..r1) -> write them from registers.
// ---------------------------------------------------------------------------
__global__ __launch_bounds__(256) void prep_kernel(const float2* __restrict__ s,
                                                   const int* __restrict__ dst,
                                                   const int* __restrict__ row_ptr,
                                                   float2* __restrict__ w23, int n) {
    const int t = threadIdx.x;
    const int l = t & 63;
    const int i = blockIdx.x * 4 + (t >> 6);
    if (i >= n) return;
    const int r0 = row_ptr[i], r1 = row_ptr[i + 1];
    const int deg = r1 - r0;
    if (deg == 0) return;

    if (deg <= 64) {
        float g2 = -INFINITY, g3 = -INFINITY;
        if (l < deg) {
            float2 sv = s[dst[r0 + l]];
            g2 = sv.x; g3 = sv.y;
        }
        float m2 = g2, m3 = g3;
        #pragma unroll
        for (int o = 1; o < 64; o <<= 1) {
            m2 = fmaxf(m2, __shfl_xor(m2, o));
            m3 = fmaxf(m3, __shfl_xor(m3, o));
        }
        float p2 = (l < deg) ? __expf(g2 - m2) : 0.f;
        float p3 = (l < deg) ? __expf(g3 - m3) : 0.f;
        float S2 = p2, S3 = p3;
        #pragma unroll
        for (int o = 1; o < 64; o <<= 1) { S2 += __shfl_xor(S2, o); S3 += __shfl_xor(S3, o); }
        if (l < deg) w23[r0 + l] = make_float2(p2 / S2, p3 / S3);
    } else {
        float m2 = -INFINITY, m3 = -INFINITY;
        for (int e = r0 + l; e < r1; e += 64) {
            float2 sv = s[dst[e]];
            m2 = fmaxf(m2, sv.x); m3 = fmaxf(m3, sv.y);
        }
        #pragma unroll
        for (int o = 1; o < 64; o <<= 1) {
            m2 = fmaxf(m2, __shfl_xor(m2, o));
            m3 = fmaxf(m3, __shfl_xor(m3, o));
        }
        float S2 = 0.f, S3 = 0.f;
        for (int e = r0 + l; e < r1; e += 64) {
            float2 sv = s[dst[e]];
            S2 += __expf(sv.x - m2); S3 += __expf(sv.y - m3);
        }
        #pragma unroll
        for (int o = 1; o < 64; o <<= 1) { S2 += __shfl_xor(S2, o); S3 += __shfl_xor(S3, o); }
        const float i2 = 1.f / S2, i3 = 1.f / S3;
        for (int e = r0 + l; e < r1; e += 64) {
            float2 sv = s[dst[e]];
            w23[e] = make_float2(__expf(sv.x - m2) * i2, __expf(sv.y - m3) * i3);
        }
    }
}

// ---------------------------------------------------------------------------
// aggregate: wave per node, lane = feature. h rows are FP16 (128 B/row = 2
// cache lines per edge, half the gather path of fp32). Edge scalars (dst,
// w2, w3) at wave-uniform addresses -> s_load; weights as SGPR operands.
// Masked 8-blocks: 8 ushort gathers in flight, no serial tail.
// ---------------------------------------------------------------------------
__global__ __launch_bounds__(256) void aggregate_kernel(const __half* __restrict__ hfeat,
                                                        const int* __restrict__ dst,
                                                        const float2* __restrict__ w23,
                                                        const int* __restrict__ row_ptr,
                                                        float* __restrict__ out,
                                                        int final_layer, int n) {
    const int t = threadIdx.x;
    const int l = t & 63;
    const int i = blockIdx.x * 4 + (t >> 6);
    if (i >= n) return;
    const int r0 = __builtin_amdgcn_readfirstlane(row_ptr[i]);
    const int r1 = __builtin_amdgcn_readfirstlane(row_ptr[i + 1]);
    const int deg = r1 - r0;

    if (deg == 0) {
        if (!final_layer) {
            out[(long)i * 192 + l] = 0.f;
            out[(long)i * 192 + 64 + l] = 0.f;
            out[(long)i * 192 + 128 + l] = 0.f;
        } else {
            out[(long)i * 64 + l] = 0.f;
        }
        return;
    }

    const float inv_deg = 1.f / (float)deg;
    float accm = 0.f, acc2 = 0.f, acc3 = 0.f;

    for (int j = r0; j < r1; j += 8) {
        int dd[8];
        float wm[8], w2[8], w3[8];
        #pragma unroll
        for (int q = 0; q < 8; ++q) {
            int jq = j + q;
            int jc = jq < r1 ? jq : r1 - 1;   // scalar clamp
            dd[q] = dst[jc];                  // uniform -> s_load
            float2 wv = w23[jc];              // uniform -> s_load_dwordx2
            bool valid = jq < r1;
            wm[q] = valid ? 1.f : 0.f;
            w2[q] = valid ? wv.x : 0.f;
            w3[q] = valid ? wv.y : 0.f;
        }
        float hv[8];
        #pragma unroll
        for (int q = 0; q < 8; ++q)
            hv[q] = __half2float(hfeat[(long)dd[q] * 64 + l]);
        #pragma unroll
        for (int q = 0; q < 8; ++q) {
            accm += wm[q] * hv[q];
            acc2 += w2[q] * hv[q];
            acc3 += w3[q] * hv[q];
        }
    }

    if (!final_layer) {
        out[(long)i * 192 + l]       = fmaxf(accm * inv_deg, 0.f);
        out[(long)i * 192 + 64 + l]  = fmaxf(acc2, 0.f);
        out[(long)i * 192 + 128 + l] = fmaxf(acc3, 0.f);
    } else {
        out[(long)i * 64 + l] = fmaxf(0.5f * inv_deg * accm + 0.25f * (acc2 + acc3), 0.f);
    }
}

// ---------------------------------------------------------------------------
extern "C" void kernel_launch(void* const* d_in, const int* in_sizes, int n_in,
                              void* d_out, int out_size, void* d_ws, size_t ws_size,
                              hipStream_t stream) {
    const float* x = (const float*)d_in[0];
    const float* lw[3] = {(const float*)d_in[1], (const float*)d_in[5], (const float*)d_in[9]};
    const float* lb[3] = {(const float*)d_in[2], (const float*)d_in[6], (const float*)d_in[10]};
    const float* aw[3] = {(const float*)d_in[3], (const float*)d_in[7], (const float*)d_in[11]};
    const int* src = (const int*)d_in[13];
    const int* dst = (const int*)d_in[14];
    float* out = (float*)d_out;

    const int N = N_NODES, E = N_EDGES;

    // ws layout:
    //   bufA: N*192 fp32 | hbuf: N*64 fp16 | sbuf: N float2 | w23: E float2
    //   | w1p,w2p: 64*192 fp32 each | row_ptr: N+1 int      (~52 MB total)
    float* bufA = (float*)d_ws;
    __half* hbuf = (__half*)(bufA + (size_t)N * 192);
    float2* sbuf = (float2*)(hbuf + (size_t)N * 64);
    float2* w23 = sbuf + N;
    float* w1p = (float*)(w23 + E);
    float* w2p = w1p + 64 * 192;
    int* row_ptr = (int*)(w2p + 64 * 192);

    rowptr_kernel<<<(N + 1 + 255) / 256, 256, 0, stream>>>(src, row_ptr, N, E);
    wprep_kernel<<<dim3(48, 2), 256, 0, stream>>>(lw[1], lw[2], w1p, w2p);

    const int lin_grid = (N + 63) / 64;
    const int node_grid = (N + 3) / 4;

    // ---- layer 0 ----
    lin_kernel<128><<<lin_grid, 128, 0, stream>>>(x, lw[0], lb[0], aw[0], hbuf, sbuf, N);
    prep_kernel<<<node_grid, 256, 0, stream>>>(sbuf, dst, row_ptr, w23, N);
    aggregate_kernel<<<node_grid, 256, 0, stream>>>(hbuf, dst, w23, row_ptr, bufA, 0, N);

    // ---- layer 1 ----
    lin_kernel<192><<<lin_grid, 128, 0, stream>>>(bufA, w1p, lb[1], aw[1], hbuf, sbuf, N);
    prep_kernel<<<node_grid, 256, 0, stream>>>(sbuf, dst, row_ptr, w23, N);
    aggregate_kernel<<<node_grid, 256, 0, stream>>>(hbuf, dst, w23, row_ptr, bufA, 0, N);

    // ---- layer 2 (final) ----
    lin_kernel<192><<<lin_grid, 128, 0, stream>>>(bufA, w2p, lb[2], aw[2], hbuf, sbuf, N);
    prep_kernel<<<node_grid, 256, 0, stream>>>(sbuf, dst, row_ptr, w23, N);
    aggregate_kernel<<<node_grid, 256, 0, stream>>>(hbuf, dst, w23, row_ptr, out, 1, N);
}

// Round 8
// 318.370 us; speedup vs baseline: 1.1350x; 1.0634x over previous
//
#include <hip/hip_runtime.h>
#include <hip/hip_fp16.h>

#define N_NODES 50000
#define N_EDGES 800000

typedef _Float16 half8 __attribute__((ext_vector_type(8)));
typedef float floatx4 __attribute__((ext_vector_type(4)));

// ---------------------------------------------------------------------------
// row_ptr[i] = lower_bound(src, i); src is sorted. row_ptr[N] = E.
// ---------------------------------------------------------------------------
__global__ __launch_bounds__(256) void rowptr_kernel(const int* __restrict__ src,
                                                     int* __restrict__ row_ptr,
                                                     int n, int e) {
    int i = blockIdx.x * 256 + threadIdx.x;
    if (i > n) return;
    int lo = 0, hi = e;
    while (lo < hi) {
        int mid = (lo + hi) >> 1;
        if (src[mid] < i) lo = mid + 1; else hi = mid;
    }
    row_ptr[i] = lo;
}

// ---------------------------------------------------------------------------
// Weight prep (all fp16 out):
//  y=0: w0p = cast(lw0)                          (64 x 128)
//  y=1: w1p = fold(lw1) to planar K=192          (64 x 192)
//  y=2: w2p = fold(lw2) to planar K=192
// Fold: agg output layout [i, c*64+f], c in {0:mean(heads0+1), 1:a2, 2:a3}.
// ---------------------------------------------------------------------------
__global__ __launch_bounds__(256) void wprep_kernel(const float* __restrict__ lw0,
                                                    const float* __restrict__ lw1,
                                                    const float* __restrict__ lw2,
                                                    _Float16* __restrict__ w0p,
                                                    _Float16* __restrict__ w1p,
                                                    _Float16* __restrict__ w2p) {
    int idx = blockIdx.x * 256 + threadIdx.x;
    if (blockIdx.y == 0) {
        if (idx < 64 * 128) w0p[idx] = (_Float16)lw0[idx];
        return;
    }
    if (idx >= 64 * 192) return;
    int o = idx / 192, r = idx % 192;
    int c = r >> 6, f = r & 63;
    const float* lw = (blockIdx.y == 1) ? lw1 : lw2;
    float v;
    if (c == 0)      v = lw[o * 256 + f * 4 + 0] + lw[o * 256 + f * 4 + 1];
    else if (c == 1) v = lw[o * 256 + f * 4 + 2];
    else             v = lw[o * 256 + f * 4 + 3];
    (blockIdx.y == 1 ? w1p : w2p)[idx] = (_Float16)v;
}

// ---------------------------------------------------------------------------
// lin via MFMA 16x16x32 f16: h[i,o] = leaky_relu(x[i,:].w[o,:]+b[o]), fp16 out.
// 256 threads = 4 waves; wave handles 16 rows x 64 cols (4 col-tiles).
// Fragments are DIRECT global loads (no LDS, no barriers):
//   A[m=lane&15][k=(lane>>4)*8+j]  <- in[row][ks..ks+7]      (16B contiguous)
//   B[k=(lane>>4)*8+j][n=lane&15]  <- w[n][ks..ks+7]         (16B, L1-hot)
// C/D: col = ct*16 + (lane&15), row = (lane>>4)*4 + reg.
// Fused score epilogue: q2/q3 partial over col-tiles, xor-reduce over lane&15.
// ---------------------------------------------------------------------------
template <typename TIn, int K>
__global__ __launch_bounds__(256) void lin_kernel(const TIn* __restrict__ in,
                                                  const _Float16* __restrict__ w,
                                                  const float* __restrict__ b,
                                                  const float* __restrict__ aw,
                                                  _Float16* __restrict__ h,
                                                  float2* __restrict__ s, int n) {
    const int t = threadIdx.x;
    const int l = t & 63;
    const int wv = t >> 6;              // wave 0..3
    const int arow = l & 15;
    const int kg = l >> 4;              // 0..3
    const long rowbase = (long)blockIdx.x * 64 + wv * 16;
    long arow_g = rowbase + arow;
    if (arow_g >= n) arow_g = n - 1;    // clamp; stores guarded below

    floatx4 acc[4] = {};

    for (int kc = 0; kc < K; kc += 32) {
        const int ks = kc + kg * 8;
        half8 a;
        if (sizeof(TIn) == 4) {
            const TIn* ap = in + arow_g * K + ks;
            #pragma unroll
            for (int j = 0; j < 8; ++j) a[j] = (_Float16)ap[j];
        } else {
            a = *(const half8*)((const _Float16*)in + arow_g * K + ks);
        }
        #pragma unroll
        for (int ct = 0; ct < 4; ++ct) {
            half8 bb = *(const half8*)(w + (long)(ct * 16 + arow) * K + ks);
            acc[ct] = __builtin_amdgcn_mfma_f32_16x16x32_f16(a, bb, acc[ct], 0, 0, 0);
        }
    }

    // epilogue
    const int c = l & 15;               // col within tile
    const int rq = l >> 4;              // row quad
    float bias[4], a2c[4], a3c[4];
    #pragma unroll
    for (int ct = 0; ct < 4; ++ct) {
        int col = ct * 16 + c;
        bias[ct] = b[col];
        a2c[ct] = aw[2 * 128 + col] + aw[2 * 128 + 64 + col];
        a3c[ct] = aw[3 * 128 + col] + aw[3 * 128 + 64 + col];
    }
    #pragma unroll
    for (int r = 0; r < 4; ++r) {
        long row = rowbase + rq * 4 + r;
        bool ok = row < n;
        float q2 = 0.f, q3 = 0.f;
        _Float16 hv[4];
        #pragma unroll
        for (int ct = 0; ct < 4; ++ct) {
            float u = acc[ct][r] + bias[ct];
            u = u > 0.f ? u : 0.2f * u;
            q2 += u * a2c[ct];
            q3 += u * a3c[ct];
            hv[ct] = (_Float16)u;
        }
        if (ok) {
            #pragma unroll
            for (int ct = 0; ct < 4; ++ct) h[row * 64 + ct * 16 + c] = hv[ct];
        }
        #pragma unroll
        for (int o = 1; o < 16; o <<= 1) {
            q2 += __shfl_xor(q2, o);
            q3 += __shfl_xor(q3, o);
        }
        if (c == 0 && ok) s[row] = make_float2(q2, q3);
    }
}

// ---------------------------------------------------------------------------
// prep: per-node softmax stats AND per-edge normalized weights in one pass.
// Wave per node; w23[r0..r1) written straight from the softmax registers.
// ---------------------------------------------------------------------------
__global__ __launch_bounds__(256) void prep_kernel(const float2* __restrict__ s,
                                                   const int* __restrict__ dst,
                                                   const int* __restrict__ row_ptr,
                                                   float2* __restrict__ w23, int n) {
    const int t = threadIdx.x;
    const int l = t & 63;
    const int i = blockIdx.x * 4 + (t >> 6);
    if (i >= n) return;
    const int r0 = row_ptr[i], r1 = row_ptr[i + 1];
    const int deg = r1 - r0;
    if (deg == 0) return;

    if (deg <= 64) {
        float g2 = -INFINITY, g3 = -INFINITY;
        if (l < deg) {
            float2 sv = s[dst[r0 + l]];
            g2 = sv.x; g3 = sv.y;
        }
        float m2 = g2, m3 = g3;
        #pragma unroll
        for (int o = 1; o < 64; o <<= 1) {
            m2 = fmaxf(m2, __shfl_xor(m2, o));
            m3 = fmaxf(m3, __shfl_xor(m3, o));
        }
        float p2 = (l < deg) ? __expf(g2 - m2) : 0.f;
        float p3 = (l < deg) ? __expf(g3 - m3) : 0.f;
        float S2 = p2, S3 = p3;
        #pragma unroll
        for (int o = 1; o < 64; o <<= 1) { S2 += __shfl_xor(S2, o); S3 += __shfl_xor(S3, o); }
        if (l < deg) w23[r0 + l] = make_float2(p2 / S2, p3 / S3);
    } else {
        float m2 = -INFINITY, m3 = -INFINITY;
        for (int e = r0 + l; e < r1; e += 64) {
            float2 sv = s[dst[e]];
            m2 = fmaxf(m2, sv.x); m3 = fmaxf(m3, sv.y);
        }
        #pragma unroll
        for (int o = 1; o < 64; o <<= 1) {
            m2 = fmaxf(m2, __shfl_xor(m2, o));
            m3 = fmaxf(m3, __shfl_xor(m3, o));
        }
        float S2 = 0.f, S3 = 0.f;
        for (int e = r0 + l; e < r1; e += 64) {
            float2 sv = s[dst[e]];
            S2 += __expf(sv.x - m2); S3 += __expf(sv.y - m3);
        }
        #pragma unroll
        for (int o = 1; o < 64; o <<= 1) { S2 += __shfl_xor(S2, o); S3 += __shfl_xor(S3, o); }
        const float i2 = 1.f / S2, i3 = 1.f / S3;
        for (int e = r0 + l; e < r1; e += 64) {
            float2 sv = s[dst[e]];
            w23[e] = make_float2(__expf(sv.x - m2) * i2, __expf(sv.y - m3) * i3);
        }
    }
}

// ---------------------------------------------------------------------------
// aggregate: wave per node, lane = feature. h rows fp16 (128 B = 2 lines per
// edge). Edge scalars at wave-uniform addresses -> s_load, SGPR weights.
// Masked 8-blocks: 8 gathers in flight, no serial tail.
// Non-final: writes fp16 bufA [i, c*64+f] (3 channels). Final: fp32 out.
// ---------------------------------------------------------------------------
__global__ __launch_bounds__(256) void aggregate_kernel(const _Float16* __restrict__ hfeat,
                                                        const int* __restrict__ dst,
                                                        const float2* __restrict__ w23,
                                                        const int* __restrict__ row_ptr,
                                                        _Float16* __restrict__ out_h,
                                                        float* __restrict__ out_f,
                                                        int final_layer, int n) {
    const int t = threadIdx.x;
    const int l = t & 63;
    const int i = blockIdx.x * 4 + (t >> 6);
    if (i >= n) return;
    const int r0 = __builtin_amdgcn_readfirstlane(row_ptr[i]);
    const int r1 = __builtin_amdgcn_readfirstlane(row_ptr[i + 1]);
    const int deg = r1 - r0;

    if (deg == 0) {
        if (!final_layer) {
            out_h[(long)i * 192 + l] = (_Float16)0.f;
            out_h[(long)i * 192 + 64 + l] = (_Float16)0.f;
            out_h[(long)i * 192 + 128 + l] = (_Float16)0.f;
        } else {
            out_f[(long)i * 64 + l] = 0.f;
        }
        return;
    }

    const float inv_deg = 1.f / (float)deg;
    float accm = 0.f, acc2 = 0.f, acc3 = 0.f;

    for (int j = r0; j < r1; j += 8) {
        int dd[8];
        float wm[8], w2[8], w3[8];
        #pragma unroll
        for (int q = 0; q < 8; ++q) {
            int jq = j + q;
            int jc = jq < r1 ? jq : r1 - 1;   // scalar clamp
            dd[q] = dst[jc];                  // uniform -> s_load
            float2 wv = w23[jc];              // uniform -> s_load_dwordx2
            bool valid = jq < r1;
            wm[q] = valid ? 1.f : 0.f;
            w2[q] = valid ? wv.x : 0.f;
            w3[q] = valid ? wv.y : 0.f;
        }
        float hv[8];
        #pragma unroll
        for (int q = 0; q < 8; ++q)
            hv[q] = (float)hfeat[(long)dd[q] * 64 + l];
        #pragma unroll
        for (int q = 0; q < 8; ++q) {
            accm += wm[q] * hv[q];
            acc2 += w2[q] * hv[q];
            acc3 += w3[q] * hv[q];
        }
    }

    if (!final_layer) {
        out_h[(long)i * 192 + l]       = (_Float16)fmaxf(accm * inv_deg, 0.f);
        out_h[(long)i * 192 + 64 + l]  = (_Float16)fmaxf(acc2, 0.f);
        out_h[(long)i * 192 + 128 + l] = (_Float16)fmaxf(acc3, 0.f);
    } else {
        out_f[(long)i * 64 + l] = fmaxf(0.5f * inv_deg * accm + 0.25f * (acc2 + acc3), 0.f);
    }
}

// ---------------------------------------------------------------------------
extern "C" void kernel_launch(void* const* d_in, const int* in_sizes, int n_in,
                              void* d_out, int out_size, void* d_ws, size_t ws_size,
                              hipStream_t stream) {
    const float* x = (const float*)d_in[0];
    const float* lw[3] = {(const float*)d_in[1], (const float*)d_in[5], (const float*)d_in[9]};
    const float* lb[3] = {(const float*)d_in[2], (const float*)d_in[6], (const float*)d_in[10]};
    const float* aw[3] = {(const float*)d_in[3], (const float*)d_in[7], (const float*)d_in[11]};
    const int* src = (const int*)d_in[13];
    const int* dst = (const int*)d_in[14];
    float* out = (float*)d_out;

    const int N = N_NODES, E = N_EDGES;

    // ws layout:
    //   bufA: N*192 fp16 | hbuf: N*64 fp16 | sbuf: N float2 | w23: E float2
    //   | w0p: 64*128 fp16 | w1p,w2p: 64*192 fp16 | row_ptr: N+1 int  (~33 MB)
    _Float16* bufA = (_Float16*)d_ws;
    _Float16* hbuf = bufA + (size_t)N * 192;
    float2* sbuf = (float2*)(hbuf + (size_t)N * 64);
    float2* w23 = sbuf + N;
    _Float16* w0p = (_Float16*)(w23 + E);
    _Float16* w1p = w0p + 64 * 128;
    _Float16* w2p = w1p + 64 * 192;
    int* row_ptr = (int*)(w2p + 64 * 192);

    rowptr_kernel<<<(N + 1 + 255) / 256, 256, 0, stream>>>(src, row_ptr, N, E);
    wprep_kernel<<<dim3(48, 3), 256, 0, stream>>>(lw[0], lw[1], lw[2], w0p, w1p, w2p);

    const int lin_grid = (N + 63) / 64;
    const int node_grid = (N + 3) / 4;

    // ---- layer 0 ----
    lin_kernel<float, 128><<<lin_grid, 256, 0, stream>>>(x, w0p, lb[0], aw[0], hbuf, sbuf, N);
    prep_kernel<<<node_grid, 256, 0, stream>>>(sbuf, dst, row_ptr, w23, N);
    aggregate_kernel<<<node_grid, 256, 0, stream>>>(hbuf, dst, w23, row_ptr, bufA, out, 0, N);

    // ---- layer 1 ----
    lin_kernel<_Float16, 192><<<lin_grid, 256, 0, stream>>>(bufA, w1p, lb[1], aw[1], hbuf, sbuf, N);
    prep_kernel<<<node_grid, 256, 0, stream>>>(sbuf, dst, row_ptr, w23, N);
    aggregate_kernel<<<node_grid, 256, 0, stream>>>(hbuf, dst, w23, row_ptr, bufA, out, 0, N);

    // ---- layer 2 (final) ----
    lin_kernel<_Float16, 192><<<lin_grid, 256, 0, stream>>>(bufA, w2p, lb[2], aw[2], hbuf, sbuf, N);
    prep_kernel<<<node_grid, 256, 0, stream>>>(sbuf, dst, row_ptr, w23, N);
    aggregate_kernel<<<node_grid, 256, 0, stream>>>(hbuf, dst, w23, row_ptr, bufA, out, 1, N);
}

// Round 9
// 270.123 us; speedup vs baseline: 1.3378x; 1.1786x over previous
//
#include <hip/hip_runtime.h>
#include <hip/hip_fp16.h>

#define N_NODES 50000
#define N_EDGES 800000

typedef _Float16 half8 __attribute__((ext_vector_type(8)));
typedef _Float16 f16x2 __attribute__((ext_vector_type(2)));
typedef float floatx4 __attribute__((ext_vector_type(4)));

// ---------------------------------------------------------------------------
// row_ptr[i] = lower_bound(src, i); src is sorted. row_ptr[N] = E.
// ---------------------------------------------------------------------------
__global__ __launch_bounds__(256) void rowptr_kernel(const int* __restrict__ src,
                                                     int* __restrict__ row_ptr,
                                                     int n, int e) {
    int i = blockIdx.x * 256 + threadIdx.x;
    if (i > n) return;
    int lo = 0, hi = e;
    while (lo < hi) {
        int mid = (lo + hi) >> 1;
        if (src[mid] < i) lo = mid + 1; else hi = mid;
    }
    row_ptr[i] = lo;
}

// ---------------------------------------------------------------------------
// x precast: fp32 -> fp16, fully coalesced.
// ---------------------------------------------------------------------------
__global__ __launch_bounds__(256) void xcast_kernel(const float* __restrict__ x,
                                                    _Float16* __restrict__ x16,
                                                    int total4) {
    int idx = blockIdx.x * 256 + threadIdx.x;
    if (idx >= total4) return;
    float4 v = ((const float4*)x)[idx];
    _Float16 o[4] = {(_Float16)v.x, (_Float16)v.y, (_Float16)v.z, (_Float16)v.w};
    *(float2*)(x16 + (size_t)idx * 4) = *(float2*)o;   // 8B store of 4 halves
}

// ---------------------------------------------------------------------------
// Weight prep (all fp16 out):
//  y=0: w0p = cast(lw0) (64x128); y=1/2: fold lw1/lw2 to planar K=192.
// Fold: agg output layout [i, c*64+f], c in {0:mean(heads0+1), 1:a2, 2:a3}.
// ---------------------------------------------------------------------------
__global__ __launch_bounds__(256) void wprep_kernel(const float* __restrict__ lw0,
                                                    const float* __restrict__ lw1,
                                                    const float* __restrict__ lw2,
                                                    _Float16* __restrict__ w0p,
                                                    _Float16* __restrict__ w1p,
                                                    _Float16* __restrict__ w2p) {
    int idx = blockIdx.x * 256 + threadIdx.x;
    if (blockIdx.y == 0) {
        if (idx < 64 * 128) w0p[idx] = (_Float16)lw0[idx];
        return;
    }
    if (idx >= 64 * 192) return;
    int o = idx / 192, r = idx % 192;
    int c = r >> 6, f = r & 63;
    const float* lw = (blockIdx.y == 1) ? lw1 : lw2;
    float v;
    if (c == 0)      v = lw[o * 256 + f * 4 + 0] + lw[o * 256 + f * 4 + 1];
    else if (c == 1) v = lw[o * 256 + f * 4 + 2];
    else             v = lw[o * 256 + f * 4 + 3];
    (blockIdx.y == 1 ? w1p : w2p)[idx] = (_Float16)v;
}

// ---------------------------------------------------------------------------
// lin via MFMA 16x16x32 f16 (verified layout, R8). 4 waves, 16 rows x 64 cols
// per wave, fragments direct from global (no LDS/barriers). Fused score.
// ---------------------------------------------------------------------------
template <int K>
__global__ __launch_bounds__(256) void lin_kernel(const _Float16* __restrict__ in,
                                                  const _Float16* __restrict__ w,
                                                  const float* __restrict__ b,
                                                  const float* __restrict__ aw,
                                                  _Float16* __restrict__ h,
                                                  float2* __restrict__ s, int n) {
    const int t = threadIdx.x;
    const int l = t & 63;
    const int wv = t >> 6;
    const int arow = l & 15;
    const int kg = l >> 4;
    const long rowbase = (long)blockIdx.x * 64 + wv * 16;
    long arow_g = rowbase + arow;
    if (arow_g >= n) arow_g = n - 1;

    floatx4 acc[4] = {};

    for (int kc = 0; kc < K; kc += 32) {
        const int ks = kc + kg * 8;
        half8 a = *(const half8*)(in + arow_g * K + ks);
        #pragma unroll
        for (int ct = 0; ct < 4; ++ct) {
            half8 bb = *(const half8*)(w + (long)(ct * 16 + arow) * K + ks);
            acc[ct] = __builtin_amdgcn_mfma_f32_16x16x32_f16(a, bb, acc[ct], 0, 0, 0);
        }
    }

    const int c = l & 15;
    const int rq = l >> 4;
    float bias[4], a2c[4], a3c[4];
    #pragma unroll
    for (int ct = 0; ct < 4; ++ct) {
        int col = ct * 16 + c;
        bias[ct] = b[col];
        a2c[ct] = aw[2 * 128 + col] + aw[2 * 128 + 64 + col];
        a3c[ct] = aw[3 * 128 + col] + aw[3 * 128 + 64 + col];
    }
    #pragma unroll
    for (int r = 0; r < 4; ++r) {
        long row = rowbase + rq * 4 + r;
        bool ok = row < n;
        float q2 = 0.f, q3 = 0.f;
        _Float16 hv[4];
        #pragma unroll
        for (int ct = 0; ct < 4; ++ct) {
            float u = acc[ct][r] + bias[ct];
            u = u > 0.f ? u : 0.2f * u;
            q2 += u * a2c[ct];
            q3 += u * a3c[ct];
            hv[ct] = (_Float16)u;
        }
        if (ok) {
            #pragma unroll
            for (int ct = 0; ct < 4; ++ct) h[row * 64 + ct * 16 + c] = hv[ct];
        }
        #pragma unroll
        for (int o = 1; o < 16; o <<= 1) {
            q2 += __shfl_xor(q2, o);
            q3 += __shfl_xor(q3, o);
        }
        if (c == 0 && ok) s[row] = make_float2(q2, q3);
    }
}

// ---------------------------------------------------------------------------
// Fused softmax + aggregation. Wave per node (4/block), wave-private LDS.
// Phase A (lane = edge): gather s[dst], 64-lane softmax (heads 2,3; heads
//   0,1 are uniform mean), write {dst, wm, a2, a3} float4 per edge slot;
//   pad all 64 slots (invalid: first dst, zero weights) -> no masking later.
// Phase B (pair-packed): lanes 0-31 edge j, lanes 32-63 edge j+1; lane
//   covers 2 features via one half2 load. Per edge-pair: 1 ds_read_b128
//   (half-wave broadcast) + 2 dword gathers + 6 FMA. 8 pairs unrolled.
// Cross-half shfl_xor(32) merge; lanes 0-31 write (half2 / float2).
// ---------------------------------------------------------------------------
__global__ __launch_bounds__(256) void agg_kernel(const _Float16* __restrict__ hfeat,
                                                  const float2* __restrict__ s,
                                                  const int* __restrict__ dst,
                                                  const int* __restrict__ row_ptr,
                                                  _Float16* __restrict__ out_h,
                                                  float* __restrict__ out_f,
                                                  int final_layer, int n) {
    __shared__ float4 eb_s[4][64];
    const int t = threadIdx.x;
    const int l = t & 63;
    const int wv = t >> 6;
    const int i = blockIdx.x * 4 + wv;
    if (i >= n) return;
    float4* eb = eb_s[wv];

    const int r0 = row_ptr[i], r1 = row_ptr[i + 1];
    const int deg = r1 - r0;

    if (deg == 0) {
        if (!final_layer) {
            out_h[(long)i * 192 + l] = (_Float16)0.f;
            out_h[(long)i * 192 + 64 + l] = (_Float16)0.f;
            out_h[(long)i * 192 + 128 + l] = (_Float16)0.f;
        } else {
            out_f[(long)i * 64 + l] = 0.f;
        }
        return;
    }

    const float inv_deg = 1.f / (float)deg;
    const int c = l & 31;        // feature pair: features 2c, 2c+1
    const int ph = l >> 5;       // pair half (edge parity)
    float am0 = 0.f, am1 = 0.f, a20 = 0.f, a21 = 0.f, a30 = 0.f, a31 = 0.f;

    if (deg <= 64) {
        // ---- phase A ----
        int dl = 0;
        float2 sv = make_float2(-INFINITY, -INFINITY);
        if (l < deg) {
            dl = dst[r0 + l];
            sv = s[dl];
        }
        float m2 = sv.x, m3 = sv.y;
        #pragma unroll
        for (int o = 1; o < 64; o <<= 1) {
            m2 = fmaxf(m2, __shfl_xor(m2, o));
            m3 = fmaxf(m3, __shfl_xor(m3, o));
        }
        float p2 = (l < deg) ? __expf(sv.x - m2) : 0.f;
        float p3 = (l < deg) ? __expf(sv.y - m3) : 0.f;
        float S2 = p2, S3 = p3;
        #pragma unroll
        for (int o = 1; o < 64; o <<= 1) { S2 += __shfl_xor(S2, o); S3 += __shfl_xor(S3, o); }
        int d0 = __builtin_amdgcn_readfirstlane(dl);
        int dpad = (l < deg) ? dl : d0;
        eb[l] = make_float4(__int_as_float(dpad), (l < deg) ? 1.f : 0.f, p2 / S2, p3 / S3);

        // ---- phase B ----
        const int nb = (deg + 15) >> 4;   // blocks of 16 edges (8 pairs)
        for (int blk = 0; blk < nb; ++blk) {
            #pragma unroll
            for (int q = 0; q < 8; ++q) {
                float4 e = eb[blk * 16 + q * 2 + ph];
                int d = __float_as_int(e.x);
                f16x2 hv = *(const f16x2*)(hfeat + (long)d * 64 + c * 2);
                float h0 = (float)hv.x, h1 = (float)hv.y;
                am0 += e.y * h0; am1 += e.y * h1;
                a20 += e.z * h0; a21 += e.z * h1;
                a30 += e.w * h0; a31 += e.w * h1;
            }
        }
    } else {
        // ---- generic fallback (deg > 64): strided stats, chunked phase B ----
        float m2 = -INFINITY, m3 = -INFINITY;
        for (int e = r0 + l; e < r1; e += 64) {
            float2 sv = s[dst[e]];
            m2 = fmaxf(m2, sv.x); m3 = fmaxf(m3, sv.y);
        }
        #pragma unroll
        for (int o = 1; o < 64; o <<= 1) {
            m2 = fmaxf(m2, __shfl_xor(m2, o));
            m3 = fmaxf(m3, __shfl_xor(m3, o));
        }
        float S2 = 0.f, S3 = 0.f;
        for (int e = r0 + l; e < r1; e += 64) {
            float2 sv = s[dst[e]];
            S2 += __expf(sv.x - m2); S3 += __expf(sv.y - m3);
        }
        #pragma unroll
        for (int o = 1; o < 64; o <<= 1) { S2 += __shfl_xor(S2, o); S3 += __shfl_xor(S3, o); }
        const float i2 = 1.f / S2, i3 = 1.f / S3;
        const int d0 = __builtin_amdgcn_readfirstlane(dst[r0] * 1);

        for (int c0 = r0; c0 < r1; c0 += 64) {
            const int cn = min(64, r1 - c0);
            int dl = d0;
            float p2 = 0.f, p3 = 0.f, vm = 0.f;
            if (l < cn) {
                dl = dst[c0 + l];
                float2 sv = s[dl];
                p2 = __expf(sv.x - m2) * i2;
                p3 = __expf(sv.y - m3) * i3;
                vm = 1.f;
            }
            eb[l] = make_float4(__int_as_float(dl), vm, p2, p3);
            __builtin_amdgcn_s_waitcnt(0);  // drain lds write before read (same wave)
            const int nb = (cn + 15) >> 4;
            for (int blk = 0; blk < nb; ++blk) {
                #pragma unroll
                for (int q = 0; q < 8; ++q) {
                    float4 e = eb[blk * 16 + q * 2 + ph];
                    int d = __float_as_int(e.x);
                    f16x2 hv = *(const f16x2*)(hfeat + (long)d * 64 + c * 2);
                    float h0 = (float)hv.x, h1 = (float)hv.y;
                    am0 += e.y * h0; am1 += e.y * h1;
                    a20 += e.z * h0; a21 += e.z * h1;
                    a30 += e.w * h0; a31 += e.w * h1;
                }
            }
        }
    }

    // ---- cross-half merge: lane c gets edge-half ph=1 partials ----
    am0 += __shfl_xor(am0, 32); am1 += __shfl_xor(am1, 32);
    a20 += __shfl_xor(a20, 32); a21 += __shfl_xor(a21, 32);
    a30 += __shfl_xor(a30, 32); a31 += __shfl_xor(a31, 32);

    if (ph == 0) {
        if (!final_layer) {
            f16x2 o0, o1, o2;
            o0.x = (_Float16)fmaxf(am0 * inv_deg, 0.f);
            o0.y = (_Float16)fmaxf(am1 * inv_deg, 0.f);
            o1.x = (_Float16)fmaxf(a20, 0.f);
            o1.y = (_Float16)fmaxf(a21, 0.f);
            o2.x = (_Float16)fmaxf(a30, 0.f);
            o2.y = (_Float16)fmaxf(a31, 0.f);
            *(f16x2*)(out_h + (long)i * 192 + c * 2)       = o0;
            *(f16x2*)(out_h + (long)i * 192 + 64 + c * 2)  = o1;
            *(f16x2*)(out_h + (long)i * 192 + 128 + c * 2) = o2;
        } else {
            float2 o;
            o.x = fmaxf(0.5f * inv_deg * am0 + 0.25f * (a20 + a30), 0.f);
            o.y = fmaxf(0.5f * inv_deg * am1 + 0.25f * (a21 + a31), 0.f);
            *(float2*)(out_f + (long)i * 64 + c * 2) = o;
        }
    }
}

// ---------------------------------------------------------------------------
extern "C" void kernel_launch(void* const* d_in, const int* in_sizes, int n_in,
                              void* d_out, int out_size, void* d_ws, size_t ws_size,
                              hipStream_t stream) {
    const float* x = (const float*)d_in[0];
    const float* lw[3] = {(const float*)d_in[1], (const float*)d_in[5], (const float*)d_in[9]};
    const float* lb[3] = {(const float*)d_in[2], (const float*)d_in[6], (const float*)d_in[10]};
    const float* aw[3] = {(const float*)d_in[3], (const float*)d_in[7], (const float*)d_in[11]};
    const int* src = (const int*)d_in[13];
    const int* dst = (const int*)d_in[14];
    float* out = (float*)d_out;

    const int N = N_NODES, E = N_EDGES;

    // ws layout:
    //   bufA: N*192 f16 | hbuf: N*64 f16 | x16: N*128 f16 | sbuf: N float2
    //   | w0p 64*128 f16 | w1p,w2p 64*192 f16 | row_ptr N+1 int   (~39 MB)
    _Float16* bufA = (_Float16*)d_ws;
    _Float16* hbuf = bufA + (size_t)N * 192;
    _Float16* x16 = hbuf + (size_t)N * 64;
    float2* sbuf = (float2*)(x16 + (size_t)N * 128);
    _Float16* w0p = (_Float16*)(sbuf + N);
    _Float16* w1p = w0p + 64 * 128;
    _Float16* w2p = w1p + 64 * 192;
    int* row_ptr = (int*)(w2p + 64 * 192);

    rowptr_kernel<<<(N + 1 + 255) / 256, 256, 0, stream>>>(src, row_ptr, N, E);
    wprep_kernel<<<dim3(48, 3), 256, 0, stream>>>(lw[0], lw[1], lw[2], w0p, w1p, w2p);
    xcast_kernel<<<(N * 128 / 4 + 255) / 256, 256, 0, stream>>>(x, x16, N * 128 / 4);

    const int lin_grid = (N + 63) / 64;
    const int node_grid = (N + 3) / 4;

    // ---- layer 0 ----
    lin_kernel<128><<<lin_grid, 256, 0, stream>>>(x16, w0p, lb[0], aw[0], hbuf, sbuf, N);
    agg_kernel<<<node_grid, 256, 0, stream>>>(hbuf, sbuf, dst, row_ptr, bufA, out, 0, N);

    // ---- layer 1 ----
    lin_kernel<192><<<lin_grid, 256, 0, stream>>>(bufA, w1p, lb[1], aw[1], hbuf, sbuf, N);
    agg_kernel<<<node_grid, 256, 0, stream>>>(hbuf, sbuf, dst, row_ptr, bufA, out, 0, N);

    // ---- layer 2 (final) ----
    lin_kernel<192><<<lin_grid, 256, 0, stream>>>(bufA, w2p, lb[2], aw[2], hbuf, sbuf, N);
    agg_kernel<<<node_grid, 256, 0, stream>>>(hbuf, sbuf, dst, row_ptr, bufA, out, 1, N);
}

// Round 10
// 265.172 us; speedup vs baseline: 1.3628x; 1.0187x over previous
//
#include <hip/hip_runtime.h>
#include <hip/hip_fp16.h>

#define N_NODES 50000
#define N_EDGES 800000

typedef _Float16 half8 __attribute__((ext_vector_type(8)));
typedef _Float16 f16x2 __attribute__((ext_vector_type(2)));
typedef float floatx4 __attribute__((ext_vector_type(4)));

// ---------------------------------------------------------------------------
// setup: y=0 rowptr (lower_bound over sorted src); y=1 cast lw0 -> fp16;
//        y=2/3 fold lw1/lw2 (64x256) to planar K=192 fp16 matching agg layout
//        [i, ch*64+f], ch in {0:mean(heads0+1), 1:a2, 2:a3}.
// ---------------------------------------------------------------------------
__global__ __launch_bounds__(256) void setup_kernel(const int* __restrict__ src,
                                                    int* __restrict__ row_ptr,
                                                    const float* __restrict__ lw0,
                                                    const float* __restrict__ lw1,
                                                    const float* __restrict__ lw2,
                                                    _Float16* __restrict__ w0p,
                                                    _Float16* __restrict__ w1p,
                                                    _Float16* __restrict__ w2p) {
    int idx = blockIdx.x * 256 + threadIdx.x;
    if (blockIdx.y == 0) {
        if (idx > N_NODES) return;
        int lo = 0, hi = N_EDGES;
        while (lo < hi) {
            int mid = (lo + hi) >> 1;
            if (src[mid] < idx) lo = mid + 1; else hi = mid;
        }
        row_ptr[idx] = lo;
        return;
    }
    if (blockIdx.y == 1) {
        if (idx < 64 * 128) w0p[idx] = (_Float16)lw0[idx];
        return;
    }
    if (idx >= 64 * 192) return;
    int o = idx / 192, r = idx % 192;
    int ch = r >> 6, f = r & 63;
    const float* lw = (blockIdx.y == 2) ? lw1 : lw2;
    float v;
    if (ch == 0)      v = lw[o * 256 + f * 4 + 0] + lw[o * 256 + f * 4 + 1];
    else if (ch == 1) v = lw[o * 256 + f * 4 + 2];
    else              v = lw[o * 256 + f * 4 + 3];
    (blockIdx.y == 2 ? w1p : w2p)[idx] = (_Float16)v;
}

// ---------------------------------------------------------------------------
// lin via MFMA 16x16x32 f16 (layout verified R8). 4 waves, 16 rows x 64 cols
// per wave, fragments direct from global. TIn=float folds the x cast in.
// Fused score epilogue.
// ---------------------------------------------------------------------------
template <typename TIn, int K>
__global__ __launch_bounds__(256) void lin_kernel(const TIn* __restrict__ in,
                                                  const _Float16* __restrict__ w,
                                                  const float* __restrict__ b,
                                                  const float* __restrict__ aw,
                                                  _Float16* __restrict__ h,
                                                  float2* __restrict__ s, int n) {
    const int t = threadIdx.x;
    const int l = t & 63;
    const int wv = t >> 6;
    const int arow = l & 15;
    const int kg = l >> 4;
    const long rowbase = (long)blockIdx.x * 64 + wv * 16;
    long arow_g = rowbase + arow;
    if (arow_g >= n) arow_g = n - 1;

    floatx4 acc[4] = {};

    for (int kc = 0; kc < K; kc += 32) {
        const int ks = kc + kg * 8;
        half8 a;
        if (sizeof(TIn) == 4) {
            const TIn* ap = in + arow_g * K + ks;
            #pragma unroll
            for (int j = 0; j < 8; ++j) a[j] = (_Float16)ap[j];
        } else {
            a = *(const half8*)((const _Float16*)in + arow_g * K + ks);
        }
        #pragma unroll
        for (int ct = 0; ct < 4; ++ct) {
            half8 bb = *(const half8*)(w + (long)(ct * 16 + arow) * K + ks);
            acc[ct] = __builtin_amdgcn_mfma_f32_16x16x32_f16(a, bb, acc[ct], 0, 0, 0);
        }
    }

    const int c = l & 15;
    const int rq = l >> 4;
    float bias[4], a2c[4], a3c[4];
    #pragma unroll
    for (int ct = 0; ct < 4; ++ct) {
        int col = ct * 16 + c;
        bias[ct] = b[col];
        a2c[ct] = aw[2 * 128 + col] + aw[2 * 128 + 64 + col];
        a3c[ct] = aw[3 * 128 + col] + aw[3 * 128 + 64 + col];
    }
    #pragma unroll
    for (int r = 0; r < 4; ++r) {
        long row = rowbase + rq * 4 + r;
        bool ok = row < n;
        float q2 = 0.f, q3 = 0.f;
        _Float16 hv[4];
        #pragma unroll
        for (int ct = 0; ct < 4; ++ct) {
            float u = acc[ct][r] + bias[ct];
            u = u > 0.f ? u : 0.2f * u;
            q2 += u * a2c[ct];
            q3 += u * a3c[ct];
            hv[ct] = (_Float16)u;
        }
        if (ok) {
            #pragma unroll
            for (int ct = 0; ct < 4; ++ct) h[row * 64 + ct * 16 + c] = hv[ct];
        }
        #pragma unroll
        for (int o = 1; o < 16; o <<= 1) {
            q2 += __shfl_xor(q2, o);
            q3 += __shfl_xor(q3, o);
        }
        if (c == 0 && ok) s[row] = make_float2(q2, q3);
    }
}

// ---------------------------------------------------------------------------
// fused agg + next-layer lin, per 64-node tile (block = 256 thr = 4 waves).
// Agg phase (wave = node, 16 nodes/wave, R9-verified path): softmax over
// s[dst] (heads 2,3; heads 0,1 = uniform mean), pair-packed gather of fp16 h
// rows, 3-channel result -> LDS tile bufA[64][200] (stride 200 halves: lin
// ds_read_b128 A-fragments then hit banks 2-way = free).
// Lin phase: MFMA 16x16x32 over the LDS tile (A) + global weights (B),
// writes h_out + fused scores s_out. bufA never touches global memory.
// ---------------------------------------------------------------------------
__global__ __launch_bounds__(256) void fused_kernel(const _Float16* __restrict__ hfeat,
                                                    const float2* __restrict__ s,
                                                    const int* __restrict__ dst,
                                                    const int* __restrict__ row_ptr,
                                                    const _Float16* __restrict__ w,
                                                    const float* __restrict__ b,
                                                    const float* __restrict__ aw,
                                                    _Float16* __restrict__ h_out,
                                                    float2* __restrict__ s_out, int n) {
    __shared__ _Float16 bufA[64][200];
    __shared__ float4 eb_s[4][64];
    const int t = threadIdx.x;
    const int l = t & 63;
    const int wv = t >> 6;
    float4* eb = eb_s[wv];
    const int c = l & 31;        // feature pair: features 2c, 2c+1
    const int ph = l >> 5;       // edge parity half
    const int i_base = blockIdx.x * 64 + wv * 16;

    // ---- agg phase: 16 nodes per wave ----
    for (int j = 0; j < 16; ++j) {
        const int i = i_base + j;
        if (i >= n) break;
        const int r0 = row_ptr[i], r1 = row_ptr[i + 1];
        const int deg = r1 - r0;
        _Float16* brow = bufA[wv * 16 + j];

        if (deg == 0) {
            brow[l] = (_Float16)0.f;
            brow[64 + l] = (_Float16)0.f;
            brow[128 + l] = (_Float16)0.f;
            continue;
        }

        const float inv_deg = 1.f / (float)deg;
        float am0 = 0.f, am1 = 0.f, a20 = 0.f, a21 = 0.f, a30 = 0.f, a31 = 0.f;

        if (deg <= 64) {
            int dl = 0;
            float2 sv = make_float2(-INFINITY, -INFINITY);
            if (l < deg) {
                dl = dst[r0 + l];
                sv = s[dl];
            }
            float m2 = sv.x, m3 = sv.y;
            #pragma unroll
            for (int o = 1; o < 64; o <<= 1) {
                m2 = fmaxf(m2, __shfl_xor(m2, o));
                m3 = fmaxf(m3, __shfl_xor(m3, o));
            }
            float p2 = (l < deg) ? __expf(sv.x - m2) : 0.f;
            float p3 = (l < deg) ? __expf(sv.y - m3) : 0.f;
            float S2 = p2, S3 = p3;
            #pragma unroll
            for (int o = 1; o < 64; o <<= 1) { S2 += __shfl_xor(S2, o); S3 += __shfl_xor(S3, o); }
            int d0 = __builtin_amdgcn_readfirstlane(dl);
            int dpad = (l < deg) ? dl : d0;
            eb[l] = make_float4(__int_as_float(dpad), (l < deg) ? 1.f : 0.f, p2 / S2, p3 / S3);

            const int nb = (deg + 15) >> 4;
            for (int blk = 0; blk < nb; ++blk) {
                #pragma unroll
                for (int q = 0; q < 8; ++q) {
                    float4 e = eb[blk * 16 + q * 2 + ph];
                    int d = __float_as_int(e.x);
                    f16x2 hv = *(const f16x2*)(hfeat + (long)d * 64 + c * 2);
                    float h0 = (float)hv.x, h1 = (float)hv.y;
                    am0 += e.y * h0; am1 += e.y * h1;
                    a20 += e.z * h0; a21 += e.z * h1;
                    a30 += e.w * h0; a31 += e.w * h1;
                }
            }
        } else {
            float m2 = -INFINITY, m3 = -INFINITY;
            for (int e = r0 + l; e < r1; e += 64) {
                float2 sv = s[dst[e]];
                m2 = fmaxf(m2, sv.x); m3 = fmaxf(m3, sv.y);
            }
            #pragma unroll
            for (int o = 1; o < 64; o <<= 1) {
                m2 = fmaxf(m2, __shfl_xor(m2, o));
                m3 = fmaxf(m3, __shfl_xor(m3, o));
            }
            float S2 = 0.f, S3 = 0.f;
            for (int e = r0 + l; e < r1; e += 64) {
                float2 sv = s[dst[e]];
                S2 += __expf(sv.x - m2); S3 += __expf(sv.y - m3);
            }
            #pragma unroll
            for (int o = 1; o < 64; o <<= 1) { S2 += __shfl_xor(S2, o); S3 += __shfl_xor(S3, o); }
            const float i2 = 1.f / S2, i3 = 1.f / S3;
            const int d0 = __builtin_amdgcn_readfirstlane(dst[r0]);

            for (int c0 = r0; c0 < r1; c0 += 64) {
                const int cn = min(64, r1 - c0);
                int dl = d0;
                float p2 = 0.f, p3 = 0.f, vm = 0.f;
                if (l < cn) {
                    dl = dst[c0 + l];
                    float2 sv = s[dl];
                    p2 = __expf(sv.x - m2) * i2;
                    p3 = __expf(sv.y - m3) * i3;
                    vm = 1.f;
                }
                eb[l] = make_float4(__int_as_float(dl), vm, p2, p3);
                __builtin_amdgcn_s_waitcnt(0);
                const int nb = (cn + 15) >> 4;
                for (int blk = 0; blk < nb; ++blk) {
                    #pragma unroll
                    for (int q = 0; q < 8; ++q) {
                        float4 e = eb[blk * 16 + q * 2 + ph];
                        int d = __float_as_int(e.x);
                        f16x2 hv = *(const f16x2*)(hfeat + (long)d * 64 + c * 2);
                        float h0 = (float)hv.x, h1 = (float)hv.y;
                        am0 += e.y * h0; am1 += e.y * h1;
                        a20 += e.z * h0; a21 += e.z * h1;
                        a30 += e.w * h0; a31 += e.w * h1;
                    }
                }
            }
        }

        am0 += __shfl_xor(am0, 32); am1 += __shfl_xor(am1, 32);
        a20 += __shfl_xor(a20, 32); a21 += __shfl_xor(a21, 32);
        a30 += __shfl_xor(a30, 32); a31 += __shfl_xor(a31, 32);

        if (ph == 0) {
            f16x2 o0, o1, o2;
            o0.x = (_Float16)fmaxf(am0 * inv_deg, 0.f);
            o0.y = (_Float16)fmaxf(am1 * inv_deg, 0.f);
            o1.x = (_Float16)fmaxf(a20, 0.f);
            o1.y = (_Float16)fmaxf(a21, 0.f);
            o2.x = (_Float16)fmaxf(a30, 0.f);
            o2.y = (_Float16)fmaxf(a31, 0.f);
            *(f16x2*)(brow + c * 2)       = o0;
            *(f16x2*)(brow + 64 + c * 2)  = o1;
            *(f16x2*)(brow + 128 + c * 2) = o2;
        }
    }

    __syncthreads();

    // ---- lin phase: MFMA over the LDS tile (K=192) ----
    const int arow = l & 15;
    const int kg = l >> 4;
    const long rowbase = (long)blockIdx.x * 64 + wv * 16;

    floatx4 acc[4] = {};
    #pragma unroll
    for (int kc = 0; kc < 192; kc += 32) {
        const int ks = kc + kg * 8;
        half8 a = *(const half8*)&bufA[wv * 16 + arow][ks];
        #pragma unroll
        for (int ct = 0; ct < 4; ++ct) {
            half8 bb = *(const half8*)(w + (long)(ct * 16 + arow) * 192 + ks);
            acc[ct] = __builtin_amdgcn_mfma_f32_16x16x32_f16(a, bb, acc[ct], 0, 0, 0);
        }
    }

    const int cc = l & 15;
    const int rq = l >> 4;
    float bias[4], a2c[4], a3c[4];
    #pragma unroll
    for (int ct = 0; ct < 4; ++ct) {
        int col = ct * 16 + cc;
        bias[ct] = b[col];
        a2c[ct] = aw[2 * 128 + col] + aw[2 * 128 + 64 + col];
        a3c[ct] = aw[3 * 128 + col] + aw[3 * 128 + 64 + col];
    }
    #pragma unroll
    for (int r = 0; r < 4; ++r) {
        long row = rowbase + rq * 4 + r;
        bool ok = row < n;
        float q2 = 0.f, q3 = 0.f;
        _Float16 hv[4];
        #pragma unroll
        for (int ct = 0; ct < 4; ++ct) {
            float u = acc[ct][r] + bias[ct];
            u = u > 0.f ? u : 0.2f * u;
            q2 += u * a2c[ct];
            q3 += u * a3c[ct];
            hv[ct] = (_Float16)u;
        }
        if (ok) {
            #pragma unroll
            for (int ct = 0; ct < 4; ++ct) h_out[row * 64 + ct * 16 + cc] = hv[ct];
        }
        #pragma unroll
        for (int o = 1; o < 16; o <<= 1) {
            q2 += __shfl_xor(q2, o);
            q3 += __shfl_xor(q3, o);
        }
        if (cc == 0 && ok) s_out[row] = make_float2(q2, q3);
    }
}

// ---------------------------------------------------------------------------
// Final-layer aggregation (R9-verified): wave per node, pair-packed fp16
// gather, out[i,f] = relu(0.5*mean + 0.25*(a2+a3)), fp32 out.
// ---------------------------------------------------------------------------
__global__ __launch_bounds__(256) void aggf_kernel(const _Float16* __restrict__ hfeat,
                                                   const float2* __restrict__ s,
                                                   const int* __restrict__ dst,
                                                   const int* __restrict__ row_ptr,
                                                   float* __restrict__ out_f, int n) {
    __shared__ float4 eb_s[4][64];
    const int t = threadIdx.x;
    const int l = t & 63;
    const int wv = t >> 6;
    const int i = blockIdx.x * 4 + wv;
    if (i >= n) return;
    float4* eb = eb_s[wv];

    const int r0 = row_ptr[i], r1 = row_ptr[i + 1];
    const int deg = r1 - r0;

    if (deg == 0) {
        out_f[(long)i * 64 + l] = 0.f;
        return;
    }

    const float inv_deg = 1.f / (float)deg;
    const int c = l & 31;
    const int ph = l >> 5;
    float am0 = 0.f, am1 = 0.f, a20 = 0.f, a21 = 0.f, a30 = 0.f, a31 = 0.f;

    if (deg <= 64) {
        int dl = 0;
        float2 sv = make_float2(-INFINITY, -INFINITY);
        if (l < deg) {
            dl = dst[r0 + l];
            sv = s[dl];
        }
        float m2 = sv.x, m3 = sv.y;
        #pragma unroll
        for (int o = 1; o < 64; o <<= 1) {
            m2 = fmaxf(m2, __shfl_xor(m2, o));
            m3 = fmaxf(m3, __shfl_xor(m3, o));
        }
        float p2 = (l < deg) ? __expf(sv.x - m2) : 0.f;
        float p3 = (l < deg) ? __expf(sv.y - m3) : 0.f;
        float S2 = p2, S3 = p3;
        #pragma unroll
        for (int o = 1; o < 64; o <<= 1) { S2 += __shfl_xor(S2, o); S3 += __shfl_xor(S3, o); }
        int d0 = __builtin_amdgcn_readfirstlane(dl);
        int dpad = (l < deg) ? dl : d0;
        eb[l] = make_float4(__int_as_float(dpad), (l < deg) ? 1.f : 0.f, p2 / S2, p3 / S3);

        const int nb = (deg + 15) >> 4;
        for (int blk = 0; blk < nb; ++blk) {
            #pragma unroll
            for (int q = 0; q < 8; ++q) {
                float4 e = eb[blk * 16 + q * 2 + ph];
                int d = __float_as_int(e.x);
                f16x2 hv = *(const f16x2*)(hfeat + (long)d * 64 + c * 2);
                float h0 = (float)hv.x, h1 = (float)hv.y;
                am0 += e.y * h0; am1 += e.y * h1;
                a20 += e.z * h0; a21 += e.z * h1;
                a30 += e.w * h0; a31 += e.w * h1;
            }
        }
    } else {
        float m2 = -INFINITY, m3 = -INFINITY;
        for (int e = r0 + l; e < r1; e += 64) {
            float2 sv = s[dst[e]];
            m2 = fmaxf(m2, sv.x); m3 = fmaxf(m3, sv.y);
        }
        #pragma unroll
        for (int o = 1; o < 64; o <<= 1) {
            m2 = fmaxf(m2, __shfl_xor(m2, o));
            m3 = fmaxf(m3, __shfl_xor(m3, o));
        }
        float S2 = 0.f, S3 = 0.f;
        for (int e = r0 + l; e < r1; e += 64) {
            float2 sv = s[dst[e]];
            S2 += __expf(sv.x - m2); S3 += __expf(sv.y - m3);
        }
        #pragma unroll
        for (int o = 1; o < 64; o <<= 1) { S2 += __shfl_xor(S2, o); S3 += __shfl_xor(S3, o); }
        const float i2 = 1.f / S2, i3 = 1.f / S3;
        const int d0 = __builtin_amdgcn_readfirstlane(dst[r0]);

        for (int c0 = r0; c0 < r1; c0 += 64) {
            const int cn = min(64, r1 - c0);
            int dl = d0;
            float p2 = 0.f, p3 = 0.f, vm = 0.f;
            if (l < cn) {
                dl = dst[c0 + l];
                float2 sv = s[dl];
                p2 = __expf(sv.x - m2) * i2;
                p3 = __expf(sv.y - m3) * i3;
                vm = 1.f;
            }
            eb[l] = make_float4(__int_as_float(dl), vm, p2, p3);
            __builtin_amdgcn_s_waitcnt(0);
            const int nb = (cn + 15) >> 4;
            for (int blk = 0; blk < nb; ++blk) {
                #pragma unroll
                for (int q = 0; q < 8; ++q) {
                    float4 e = eb[blk * 16 + q * 2 + ph];
                    int d = __float_as_int(e.x);
                    f16x2 hv = *(const f16x2*)(hfeat + (long)d * 64 + c * 2);
                    float h0 = (float)hv.x, h1 = (float)hv.y;
                    am0 += e.y * h0; am1 += e.y * h1;
                    a20 += e.z * h0; a21 += e.z * h1;
                    a30 += e.w * h0; a31 += e.w * h1;
                }
            }
        }
    }

    am0 += __shfl_xor(am0, 32); am1 += __shfl_xor(am1, 32);
    a20 += __shfl_xor(a20, 32); a21 += __shfl_xor(a21, 32);
    a30 += __shfl_xor(a30, 32); a31 += __shfl_xor(a31, 32);

    if (ph == 0) {
        float2 o;
        o.x = fmaxf(0.5f * inv_deg * am0 + 0.25f * (a20 + a30), 0.f);
        o.y = fmaxf(0.5f * inv_deg * am1 + 0.25f * (a21 + a31), 0.f);
        *(float2*)(out_f + (long)i * 64 + c * 2) = o;
    }
}

// ---------------------------------------------------------------------------
extern "C" void kernel_launch(void* const* d_in, const int* in_sizes, int n_in,
                              void* d_out, int out_size, void* d_ws, size_t ws_size,
                              hipStream_t stream) {
    const float* x = (const float*)d_in[0];
    const float* lw[3] = {(const float*)d_in[1], (const float*)d_in[5], (const float*)d_in[9]};
    const float* lb[3] = {(const float*)d_in[2], (const float*)d_in[6], (const float*)d_in[10]};
    const float* aw[3] = {(const float*)d_in[3], (const float*)d_in[7], (const float*)d_in[11]};
    const int* src = (const int*)d_in[13];
    const int* dst = (const int*)d_in[14];
    float* out = (float*)d_out;

    const int N = N_NODES;

    // ws layout: hA,hB: N*64 f16 | sA,sB: N float2 | w0p 64*128 f16
    //            | w1p,w2p 64*192 f16 | row_ptr N+1 int   (~16 MB)
    _Float16* hA = (_Float16*)d_ws;
    _Float16* hB = hA + (size_t)N * 64;
    float2* sA = (float2*)(hB + (size_t)N * 64);
    float2* sB = sA + N;
    _Float16* w0p = (_Float16*)(sB + N);
    _Float16* w1p = w0p + 64 * 128;
    _Float16* w2p = w1p + 64 * 192;
    int* row_ptr = (int*)(w2p + 64 * 192);

    const int lin_grid = (N + 63) / 64;      // 782
    const int node_grid = (N + 3) / 4;       // 12500

    setup_kernel<<<dim3(196, 4), 256, 0, stream>>>(src, row_ptr, lw[0], lw[1], lw[2],
                                                   w0p, w1p, w2p);

    // layer 0: x (fp32, cast inline) -> hA, sA
    lin_kernel<float, 128><<<lin_grid, 256, 0, stream>>>(x, w0p, lb[0], aw[0], hA, sA, N);

    // layer 0 agg + layer 1 lin: -> hB, sB
    fused_kernel<<<lin_grid, 256, 0, stream>>>(hA, sA, dst, row_ptr, w1p, lb[1], aw[1],
                                               hB, sB, N);

    // layer 1 agg + layer 2 lin: -> hA, sA
    fused_kernel<<<lin_grid, 256, 0, stream>>>(hB, sB, dst, row_ptr, w2p, lb[2], aw[2],
                                               hA, sA, N);

    // layer 2 final aggregation -> out
    aggf_kernel<<<node_grid, 256, 0, stream>>>(hA, sA, dst, row_ptr, out, N);
}

// Round 11
// 247.861 us; speedup vs baseline: 1.4579x; 1.0698x over previous
//
#include <hip/hip_runtime.h>
#include <hip/hip_fp16.h>

#define N_NODES 50000
#define N_EDGES 800000

typedef _Float16 half8 __attribute__((ext_vector_type(8)));
typedef _Float16 f16x2 __attribute__((ext_vector_type(2)));
typedef float floatx4 __attribute__((ext_vector_type(4)));

// ---------------------------------------------------------------------------
// setup: y=0 rowptr (lower_bound over sorted src); y=1 cast lw0 -> fp16;
//        y=2/3 fold lw1/lw2 (64x256) to planar K=192 fp16 matching agg layout
//        [i, ch*64+f], ch in {0:mean(heads0+1), 1:a2, 2:a3}.
// ---------------------------------------------------------------------------
__global__ __launch_bounds__(256) void setup_kernel(const int* __restrict__ src,
                                                    int* __restrict__ row_ptr,
                                                    const float* __restrict__ lw0,
                                                    const float* __restrict__ lw1,
                                                    const float* __restrict__ lw2,
                                                    _Float16* __restrict__ w0p,
                                                    _Float16* __restrict__ w1p,
                                                    _Float16* __restrict__ w2p) {
    int idx = blockIdx.x * 256 + threadIdx.x;
    if (blockIdx.y == 0) {
        if (idx > N_NODES) return;
        int lo = 0, hi = N_EDGES;
        while (lo < hi) {
            int mid = (lo + hi) >> 1;
            if (src[mid] < idx) lo = mid + 1; else hi = mid;
        }
        row_ptr[idx] = lo;
        return;
    }
    if (blockIdx.y == 1) {
        if (idx < 64 * 128) w0p[idx] = (_Float16)lw0[idx];
        return;
    }
    if (idx >= 64 * 192) return;
    int o = idx / 192, r = idx % 192;
    int ch = r >> 6, f = r & 63;
    const float* lw = (blockIdx.y == 2) ? lw1 : lw2;
    float v;
    if (ch == 0)      v = lw[o * 256 + f * 4 + 0] + lw[o * 256 + f * 4 + 1];
    else if (ch == 1) v = lw[o * 256 + f * 4 + 2];
    else              v = lw[o * 256 + f * 4 + 3];
    (blockIdx.y == 2 ? w1p : w2p)[idx] = (_Float16)v;
}

// ---------------------------------------------------------------------------
// lin via MFMA 16x16x32 f16 (layout verified R8). 4 waves, 16 rows x 64 cols
// per wave, fragments direct from global. TIn=float folds the x cast in.
// Score epilogue now stores E = exp(score) (deferred-normalization softmax).
// ---------------------------------------------------------------------------
template <typename TIn, int K>
__global__ __launch_bounds__(256) void lin_kernel(const TIn* __restrict__ in,
                                                  const _Float16* __restrict__ w,
                                                  const float* __restrict__ b,
                                                  const float* __restrict__ aw,
                                                  _Float16* __restrict__ h,
                                                  float2* __restrict__ s, int n) {
    const int t = threadIdx.x;
    const int l = t & 63;
    const int wv = t >> 6;
    const int arow = l & 15;
    const int kg = l >> 4;
    const long rowbase = (long)blockIdx.x * 64 + wv * 16;
    long arow_g = rowbase + arow;
    if (arow_g >= n) arow_g = n - 1;

    floatx4 acc[4] = {};

    for (int kc = 0; kc < K; kc += 32) {
        const int ks = kc + kg * 8;
        half8 a;
        if (sizeof(TIn) == 4) {
            const TIn* ap = in + arow_g * K + ks;
            #pragma unroll
            for (int j = 0; j < 8; ++j) a[j] = (_Float16)ap[j];
        } else {
            a = *(const half8*)((const _Float16*)in + arow_g * K + ks);
        }
        #pragma unroll
        for (int ct = 0; ct < 4; ++ct) {
            half8 bb = *(const half8*)(w + (long)(ct * 16 + arow) * K + ks);
            acc[ct] = __builtin_amdgcn_mfma_f32_16x16x32_f16(a, bb, acc[ct], 0, 0, 0);
        }
    }

    const int c = l & 15;
    const int rq = l >> 4;
    float bias[4], a2c[4], a3c[4];
    #pragma unroll
    for (int ct = 0; ct < 4; ++ct) {
        int col = ct * 16 + c;
        bias[ct] = b[col];
        a2c[ct] = aw[2 * 128 + col] + aw[2 * 128 + 64 + col];
        a3c[ct] = aw[3 * 128 + col] + aw[3 * 128 + 64 + col];
    }
    #pragma unroll
    for (int r = 0; r < 4; ++r) {
        long row = rowbase + rq * 4 + r;
        bool ok = row < n;
        float q2 = 0.f, q3 = 0.f;
        _Float16 hv[4];
        #pragma unroll
        for (int ct = 0; ct < 4; ++ct) {
            float u = acc[ct][r] + bias[ct];
            u = u > 0.f ? u : 0.2f * u;
            q2 += u * a2c[ct];
            q3 += u * a3c[ct];
            hv[ct] = (_Float16)u;
        }
        if (ok) {
            #pragma unroll
            for (int ct = 0; ct < 4; ++ct) h[row * 64 + ct * 16 + c] = hv[ct];
        }
        #pragma unroll
        for (int o = 1; o < 16; o <<= 1) {
            q2 += __shfl_xor(q2, o);
            q3 += __shfl_xor(q3, o);
        }
        if (c == 0 && ok) s[row] = make_float2(__expf(q2), __expf(q3));
    }
}

// ---------------------------------------------------------------------------
// Single-pass aggregation with deferred softmax normalization.
// Wave per node (4/block, grid 12500, NO LDS). Lane: c = l&31 (feature pair
// -> features 2c,2c+1), ph = l>>5 (edge parity).
// Per edge-pair: dst via readlane (uniform j -> SGPR), E[d] float2 load
// (same addr across half-wave -> merged), f16x2 h load, 8 FMA/add.
// acc2/acc3 accumulate E-weighted sums; S2/S3 accumulate E sums in-register;
// one shfl_xor(32) merge at the end; normalize by 1/S at write time.
// Heads 0,1: uniform alpha -> mean channel (vm mask handles odd tails).
// deg>64 handled by the same chunk loop (S accumulates across chunks).
// ---------------------------------------------------------------------------
__global__ __launch_bounds__(256) void agg_kernel(const _Float16* __restrict__ hfeat,
                                                  const float2* __restrict__ E,
                                                  const int* __restrict__ dst,
                                                  const int* __restrict__ row_ptr,
                                                  _Float16* __restrict__ out_h,
                                                  float* __restrict__ out_f,
                                                  int final_layer, int n) {
    const int t = threadIdx.x;
    const int l = t & 63;
    const int i = blockIdx.x * 4 + (t >> 6);
    if (i >= n) return;
    const int r0 = row_ptr[i], r1 = row_ptr[i + 1];
    const int deg = r1 - r0;
    const int c = l & 31;
    const int ph = l >> 5;

    if (deg == 0) {
        if (!final_layer) {
            out_h[(long)i * 192 + l] = (_Float16)0.f;
            out_h[(long)i * 192 + 64 + l] = (_Float16)0.f;
            out_h[(long)i * 192 + 128 + l] = (_Float16)0.f;
        } else {
            out_f[(long)i * 64 + l] = 0.f;
        }
        return;
    }

    float am0 = 0.f, am1 = 0.f, a20 = 0.f, a21 = 0.f, a30 = 0.f, a31 = 0.f;
    float S2 = 0.f, S3 = 0.f;

    for (int c0 = r0; c0 < r1; c0 += 64) {
        const int cn = min(64, r1 - c0);
        const int dl = dst[c0 + min(l, cn - 1)];   // coalesced edge-id load

        for (int jj = 0; jj < cn; jj += 8) {
            // scalar-uniform edge ids + valid flags for 8 edges (4 pairs)
            int dS[8];
            float fv[8];
            #pragma unroll
            for (int q = 0; q < 8; ++q) {
                int e = jj + q;
                dS[q] = __builtin_amdgcn_readlane(dl, e < cn ? e : cn - 1);
                fv[q] = e < cn ? 1.f : 0.f;
            }
            // 4 independent pair-steps: 8 loads in flight
            int dk[4]; float vmk[4];
            #pragma unroll
            for (int k = 0; k < 4; ++k) {
                dk[k] = ph ? dS[2 * k + 1] : dS[2 * k];
                vmk[k] = ph ? fv[2 * k + 1] : fv[2 * k];
            }
            float2 Ev[4]; f16x2 hv[4];
            #pragma unroll
            for (int k = 0; k < 4; ++k) {
                Ev[k] = E[dk[k]];
                hv[k] = *(const f16x2*)(hfeat + (long)dk[k] * 64 + c * 2);
            }
            #pragma unroll
            for (int k = 0; k < 4; ++k) {
                float h0 = (float)hv[k].x, h1 = (float)hv[k].y;
                float vm = vmk[k];
                float w2 = vm * Ev[k].x, w3 = vm * Ev[k].y;
                am0 += vm * h0; am1 += vm * h1;
                a20 += w2 * h0; a21 += w2 * h1;
                a30 += w3 * h0; a31 += w3 * h1;
                S2 += w2; S3 += w3;
            }
        }
    }

    // merge the two edge-parity halves (lane c <-> lane c+32)
    am0 += __shfl_xor(am0, 32); am1 += __shfl_xor(am1, 32);
    a20 += __shfl_xor(a20, 32); a21 += __shfl_xor(a21, 32);
    a30 += __shfl_xor(a30, 32); a31 += __shfl_xor(a31, 32);
    S2  += __shfl_xor(S2, 32);  S3  += __shfl_xor(S3, 32);

    const float inv_deg = 1.f / (float)deg;
    const float i2 = 1.f / S2, i3 = 1.f / S3;

    if (ph == 0) {
        if (!final_layer) {
            f16x2 o0, o1, o2;
            o0.x = (_Float16)fmaxf(am0 * inv_deg, 0.f);
            o0.y = (_Float16)fmaxf(am1 * inv_deg, 0.f);
            o1.x = (_Float16)fmaxf(a20 * i2, 0.f);
            o1.y = (_Float16)fmaxf(a21 * i2, 0.f);
            o2.x = (_Float16)fmaxf(a30 * i3, 0.f);
            o2.y = (_Float16)fmaxf(a31 * i3, 0.f);
            *(f16x2*)(out_h + (long)i * 192 + c * 2)       = o0;
            *(f16x2*)(out_h + (long)i * 192 + 64 + c * 2)  = o1;
            *(f16x2*)(out_h + (long)i * 192 + 128 + c * 2) = o2;
        } else {
            float2 o;
            o.x = fmaxf(0.5f * inv_deg * am0 + 0.25f * (a20 * i2 + a30 * i3), 0.f);
            o.y = fmaxf(0.5f * inv_deg * am1 + 0.25f * (a21 * i2 + a31 * i3), 0.f);
            *(float2*)(out_f + (long)i * 64 + c * 2) = o;
        }
    }
}

// ---------------------------------------------------------------------------
extern "C" void kernel_launch(void* const* d_in, const int* in_sizes, int n_in,
                              void* d_out, int out_size, void* d_ws, size_t ws_size,
                              hipStream_t stream) {
    const float* x = (const float*)d_in[0];
    const float* lw[3] = {(const float*)d_in[1], (const float*)d_in[5], (const float*)d_in[9]};
    const float* lb[3] = {(const float*)d_in[2], (const float*)d_in[6], (const float*)d_in[10]};
    const float* aw[3] = {(const float*)d_in[3], (const float*)d_in[7], (const float*)d_in[11]};
    const int* src = (const int*)d_in[13];
    const int* dst = (const int*)d_in[14];
    float* out = (float*)d_out;

    const int N = N_NODES;

    // ws layout: hA,hB: N*64 f16 | g: N*192 f16 | sA,sB: N float2
    //            | w0p 64*128 f16 | w1p,w2p 64*192 f16 | row_ptr N+1 int
    _Float16* hA = (_Float16*)d_ws;
    _Float16* hB = hA + (size_t)N * 64;
    _Float16* g  = hB + (size_t)N * 64;
    float2* sA = (float2*)(g + (size_t)N * 192);
    float2* sB = sA + N;
    _Float16* w0p = (_Float16*)(sB + N);
    _Float16* w1p = w0p + 64 * 128;
    _Float16* w2p = w1p + 64 * 192;
    int* row_ptr = (int*)(w2p + 64 * 192);

    const int lin_grid = (N + 63) / 64;      // 782
    const int node_grid = (N + 3) / 4;       // 12500

    setup_kernel<<<dim3(196, 4), 256, 0, stream>>>(src, row_ptr, lw[0], lw[1], lw[2],
                                                   w0p, w1p, w2p);

    // layer 0: x (fp32, cast inline) -> hA, sA(=E)
    lin_kernel<float, 128><<<lin_grid, 256, 0, stream>>>(x, w0p, lb[0], aw[0], hA, sA, N);

    // layer 0 agg -> g ; layer 1 lin: g -> hB, sB
    agg_kernel<<<node_grid, 256, 0, stream>>>(hA, sA, dst, row_ptr, g, out, 0, N);
    lin_kernel<_Float16, 192><<<lin_grid, 256, 0, stream>>>(g, w1p, lb[1], aw[1], hB, sB, N);

    // layer 1 agg -> g ; layer 2 lin: g -> hA, sA
    agg_kernel<<<node_grid, 256, 0, stream>>>(hB, sB, dst, row_ptr, g, out, 0, N);
    lin_kernel<_Float16, 192><<<lin_grid, 256, 0, stream>>>(g, w2p, lb[2], aw[2], hA, sA, N);

    // layer 2 final aggregation -> out (fp32)
    agg_kernel<<<node_grid, 256, 0, stream>>>(hA, sA, dst, row_ptr, g, out, 1, N);
}

// Round 13
// 233.355 us; speedup vs baseline: 1.5486x; 1.0622x over previous
//
#include <hip/hip_runtime.h>
#include <hip/hip_fp16.h>

#define N_NODES 50000
#define N_EDGES 800000

typedef _Float16 half8 __attribute__((ext_vector_type(8)));
typedef _Float16 f16x4 __attribute__((ext_vector_type(4)));
typedef float floatx4 __attribute__((ext_vector_type(4)));

// ---------------------------------------------------------------------------
// setup: y=0 rowptr (lower_bound over sorted src); y=1 cast lw0 -> fp16;
//        y=2/3 fold lw1/lw2 (64x256) to planar K=192 fp16 matching agg layout
//        [i, ch*64+f], ch in {0:mean(heads0+1), 1:a2, 2:a3}.
// ---------------------------------------------------------------------------
__global__ __launch_bounds__(256) void setup_kernel(const int* __restrict__ src,
                                                    int* __restrict__ row_ptr,
                                                    const float* __restrict__ lw0,
                                                    const float* __restrict__ lw1,
                                                    const float* __restrict__ lw2,
                                                    _Float16* __restrict__ w0p,
                                                    _Float16* __restrict__ w1p,
                                                    _Float16* __restrict__ w2p) {
    int idx = blockIdx.x * 256 + threadIdx.x;
    if (blockIdx.y == 0) {
        if (idx > N_NODES) return;
        int lo = 0, hi = N_EDGES;
        while (lo < hi) {
            int mid = (lo + hi) >> 1;
            if (src[mid] < idx) lo = mid + 1; else hi = mid;
        }
        row_ptr[idx] = lo;
        return;
    }
    if (blockIdx.y == 1) {
        if (idx < 64 * 128) w0p[idx] = (_Float16)lw0[idx];
        return;
    }
    if (idx >= 64 * 192) return;
    int o = idx / 192, r = idx % 192;
    int ch = r >> 6, f = r & 63;
    const float* lw = (blockIdx.y == 2) ? lw1 : lw2;
    float v;
    if (ch == 0)      v = lw[o * 256 + f * 4 + 0] + lw[o * 256 + f * 4 + 1];
    else if (ch == 1) v = lw[o * 256 + f * 4 + 2];
    else              v = lw[o * 256 + f * 4 + 3];
    (blockIdx.y == 2 ? w1p : w2p)[idx] = (_Float16)v;
}

// ---------------------------------------------------------------------------
// lin via MFMA 16x16x32 f16 (layout verified R8). 4 waves, 16 rows x 64 cols
// per wave, fragments direct from global. TIn=float folds the x cast in.
// Score epilogue stores E = exp(score) (deferred-normalization softmax).
// ---------------------------------------------------------------------------
template <typename TIn, int K>
__global__ __launch_bounds__(256) void lin_kernel(const TIn* __restrict__ in,
                                                  const _Float16* __restrict__ w,
                                                  const float* __restrict__ b,
                                                  const float* __restrict__ aw,
                                                  _Float16* __restrict__ h,
                                                  float2* __restrict__ s, int n) {
    const int t = threadIdx.x;
    const int l = t & 63;
    const int wv = t >> 6;
    const int arow = l & 15;
    const int kg = l >> 4;
    const long rowbase = (long)blockIdx.x * 64 + wv * 16;
    long arow_g = rowbase + arow;
    if (arow_g >= n) arow_g = n - 1;

    floatx4 acc[4] = {};

    for (int kc = 0; kc < K; kc += 32) {
        const int ks = kc + kg * 8;
        half8 a;
        if (sizeof(TIn) == 4) {
            const TIn* ap = in + arow_g * K + ks;
            #pragma unroll
            for (int j = 0; j < 8; ++j) a[j] = (_Float16)ap[j];
        } else {
            a = *(const half8*)((const _Float16*)in + arow_g * K + ks);
        }
        #pragma unroll
        for (int ct = 0; ct < 4; ++ct) {
            half8 bb = *(const half8*)(w + (long)(ct * 16 + arow) * K + ks);
            acc[ct] = __builtin_amdgcn_mfma_f32_16x16x32_f16(a, bb, acc[ct], 0, 0, 0);
        }
    }

    const int c = l & 15;
    const int rq = l >> 4;
    float bias[4], a2c[4], a3c[4];
    #pragma unroll
    for (int ct = 0; ct < 4; ++ct) {
        int col = ct * 16 + c;
        bias[ct] = b[col];
        a2c[ct] = aw[2 * 128 + col] + aw[2 * 128 + 64 + col];
        a3c[ct] = aw[3 * 128 + col] + aw[3 * 128 + 64 + col];
    }
    #pragma unroll
    for (int r = 0; r < 4; ++r) {
        long row = rowbase + rq * 4 + r;
        bool ok = row < n;
        float q2 = 0.f, q3 = 0.f;
        _Float16 hv[4];
        #pragma unroll
        for (int ct = 0; ct < 4; ++ct) {
            float u = acc[ct][r] + bias[ct];
            u = u > 0.f ? u : 0.2f * u;
            q2 += u * a2c[ct];
            q3 += u * a3c[ct];
            hv[ct] = (_Float16)u;
        }
        if (ok) {
            #pragma unroll
            for (int ct = 0; ct < 4; ++ct) h[row * 64 + ct * 16 + c] = hv[ct];
        }
        #pragma unroll
        for (int o = 1; o < 16; o <<= 1) {
            q2 += __shfl_xor(q2, o);
            q3 += __shfl_xor(q3, o);
        }
        if (c == 0 && ok) s[row] = make_float2(__expf(q2), __expf(q3));
    }
}

// ---------------------------------------------------------------------------
// Single-pass aggregation, deferred softmax normalization, QUARTER-WAVE edge
// parallelism. Wave per node (4/block, grid 12500, no LDS).
// Lane: q = l>>4 (edge slot within 4-edge group), fl = l&15 (feature quad ->
// features fl*4..fl*4+3 via one f16x4 8B load; 16 lanes cover the 128B row).
// One VMEM instruction covers 4 edges. Per 8-edge step: 2 h-loads + 2 E-loads
// in flight. Edge-id distribution to quarters uses __shfl (ds_bpermute —
// per-lane index is legal; v_readlane with divergent index was the R12 bug).
// S2/S3 sum E per quarter; quarters partition edges -> xor-16/32 merge gives
// the true segment sums on every lane.
// ---------------------------------------------------------------------------
__global__ __launch_bounds__(256) void agg_kernel(const _Float16* __restrict__ hfeat,
                                                  const float2* __restrict__ E,
                                                  const int* __restrict__ dst,
                                                  const int* __restrict__ row_ptr,
                                                  _Float16* __restrict__ out_h,
                                                  float* __restrict__ out_f,
                                                  int final_layer, int n) {
    const int t = threadIdx.x;
    const int l = t & 63;
    const int i = blockIdx.x * 4 + (t >> 6);
    if (i >= n) return;
    const int r0 = row_ptr[i], r1 = row_ptr[i + 1];
    const int deg = r1 - r0;
    const int q = l >> 4;      // edge slot 0..3
    const int fl = l & 15;     // feature quad

    if (deg == 0) {
        if (!final_layer) {
            if (q < 3) *(f16x4*)(out_h + (long)i * 192 + q * 64 + fl * 4) =
                f16x4{(_Float16)0.f, (_Float16)0.f, (_Float16)0.f, (_Float16)0.f};
        } else if (q == 0) {
            *(floatx4*)(out_f + (long)i * 64 + fl * 4) = floatx4{0.f, 0.f, 0.f, 0.f};
        }
        return;
    }

    float am[4] = {}, a2[4] = {}, a3[4] = {};
    float S2 = 0.f, S3 = 0.f;

    for (int c0 = r0; c0 < r1; c0 += 64) {
        const int cn = min(64, r1 - c0);
        const int dl = dst[c0 + min(l, cn - 1)];   // coalesced edge-id load

        for (int jj = 0; jj < cn; jj += 8) {
            // two 4-edge groups; this lane handles edge jj + g*4 + q
            int dg[2]; float vg[2];
            #pragma unroll
            for (int g = 0; g < 2; ++g) {
                int e = jj + g * 4 + q;
                int ec = e < cn ? e : cn - 1;
                dg[g] = __shfl(dl, ec);            // ds_bpermute: per-lane idx OK
                vg[g] = e < cn ? 1.f : 0.f;
            }
            f16x4 hv[2]; float2 Ev[2];
            #pragma unroll
            for (int g = 0; g < 2; ++g) {
                hv[g] = *(const f16x4*)(hfeat + (long)dg[g] * 64 + fl * 4);
                Ev[g] = E[dg[g]];
            }
            #pragma unroll
            for (int g = 0; g < 2; ++g) {
                float vm = vg[g];
                float e2 = vm * Ev[g].x, e3 = vm * Ev[g].y;
                S2 += e2; S3 += e3;
                #pragma unroll
                for (int k = 0; k < 4; ++k) {
                    float hf = (float)hv[g][k];
                    am[k] += vm * hf;
                    a2[k] += e2 * hf;
                    a3[k] += e3 * hf;
                }
            }
        }
    }

    // merge quarters: lanes {fl, fl+16, fl+32, fl+48} all get the group sum
    #pragma unroll
    for (int o = 16; o < 64; o <<= 1) {
        #pragma unroll
        for (int k = 0; k < 4; ++k) {
            am[k] += __shfl_xor(am[k], o);
            a2[k] += __shfl_xor(a2[k], o);
            a3[k] += __shfl_xor(a3[k], o);
        }
        S2 += __shfl_xor(S2, o);
        S3 += __shfl_xor(S3, o);
    }

    const float inv_deg = 1.f / (float)deg;
    const float i2 = 1.f / S2, i3 = 1.f / S3;

    if (!final_layer) {
        if (q == 0) {
            f16x4 o0, o1, o2;
            #pragma unroll
            for (int k = 0; k < 4; ++k) {
                o0[k] = (_Float16)fmaxf(am[k] * inv_deg, 0.f);
                o1[k] = (_Float16)fmaxf(a2[k] * i2, 0.f);
                o2[k] = (_Float16)fmaxf(a3[k] * i3, 0.f);
            }
            *(f16x4*)(out_h + (long)i * 192 + fl * 4)       = o0;
            *(f16x4*)(out_h + (long)i * 192 + 64 + fl * 4)  = o1;
            *(f16x4*)(out_h + (long)i * 192 + 128 + fl * 4) = o2;
        }
    } else {
        if (q == 0) {
            floatx4 o;
            #pragma unroll
            for (int k = 0; k < 4; ++k)
                o[k] = fmaxf(0.5f * inv_deg * am[k] + 0.25f * (a2[k] * i2 + a3[k] * i3), 0.f);
            *(floatx4*)(out_f + (long)i * 64 + fl * 4) = o;
        }
    }
}

// ---------------------------------------------------------------------------
extern "C" void kernel_launch(void* const* d_in, const int* in_sizes, int n_in,
                              void* d_out, int out_size, void* d_ws, size_t ws_size,
                              hipStream_t stream) {
    const float* x = (const float*)d_in[0];
    const float* lw[3] = {(const float*)d_in[1], (const float*)d_in[5], (const float*)d_in[9]};
    const float* lb[3] = {(const float*)d_in[2], (const float*)d_in[6], (const float*)d_in[10]};
    const float* aw[3] = {(const float*)d_in[3], (const float*)d_in[7], (const float*)d_in[11]};
    const int* src = (const int*)d_in[13];
    const int* dst = (const int*)d_in[14];
    float* out = (float*)d_out;

    const int N = N_NODES;

    // ws layout: hA,hB: N*64 f16 | g: N*192 f16 | sA,sB: N float2
    //            | w0p 64*128 f16 | w1p,w2p 64*192 f16 | row_ptr N+1 int
    _Float16* hA = (_Float16*)d_ws;
    _Float16* hB = hA + (size_t)N * 64;
    _Float16* g  = hB + (size_t)N * 64;
    float2* sA = (float2*)(g + (size_t)N * 192);
    float2* sB = sA + N;
    _Float16* w0p = (_Float16*)(sB + N);
    _Float16* w1p = w0p + 64 * 128;
    _Float16* w2p = w1p + 64 * 192;
    int* row_ptr = (int*)(w2p + 64 * 192);

    const int lin_grid = (N + 63) / 64;      // 782
    const int node_grid = (N + 3) / 4;       // 12500

    setup_kernel<<<dim3(196, 4), 256, 0, stream>>>(src, row_ptr, lw[0], lw[1], lw[2],
                                                   w0p, w1p, w2p);

    // layer 0: x (fp32, cast inline) -> hA, sA(=E)
    lin_kernel<float, 128><<<lin_grid, 256, 0, stream>>>(x, w0p, lb[0], aw[0], hA, sA, N);

    // layer 0 agg -> g ; layer 1 lin: g -> hB, sB
    agg_kernel<<<node_grid, 256, 0, stream>>>(hA, sA, dst, row_ptr, g, out, 0, N);
    lin_kernel<_Float16, 192><<<lin_grid, 256, 0, stream>>>(g, w1p, lb[1], aw[1], hB, sB, N);

    // layer 1 agg -> g ; layer 2 lin: g -> hA, sA
    agg_kernel<<<node_grid, 256, 0, stream>>>(hB, sB, dst, row_ptr, g, out, 0, N);
    lin_kernel<_Float16, 192><<<lin_grid, 256, 0, stream>>>(g, w2p, lb[2], aw[2], hA, sA, N);

    // layer 2 final aggregation -> out (fp32)
    agg_kernel<<<node_grid, 256, 0, stream>>>(hA, sA, dst, row_ptr, g, out, 1, N);
}